// Round 8
// baseline (1370.189 us; speedup 1.0000x reference)
//
#include <hip/hip_runtime.h>

#define LTOT 21952      // 28^3
#define NTOK 343        // 7^3

typedef unsigned short u16;
typedef unsigned int   u32;
typedef __attribute__((ext_vector_type(8))) short short8;
typedef __attribute__((ext_vector_type(4))) float float4v;

__device__ __forceinline__ u16 f2b(float f){
  u32 x = __float_as_uint(f);
  u32 r = (x + 0x7fffu + ((x>>16)&1u)) >> 16;
  return (u16)r;
}

// 16B global -> LDS direct DMA (HW dest = wave-uniform base + lane*16)
__device__ __forceinline__ void dma16(const u16* g, u16* l){
  __builtin_amdgcn_global_load_lds((const __attribute__((address_space(1))) u32*)g,
                                   (__attribute__((address_space(3))) u32*)l,
                                   16, 0, 0);
}

// ---------------- LayerNorm (norm1) : f32 in -> f32 out --------------------
__global__ __launch_bounds__(64) void k_ln(const float* __restrict__ mov, const float* __restrict__ fix,
                                           const float* __restrict__ g, const float* __restrict__ b,
                                           float* __restrict__ om, float* __restrict__ of){
  int row = blockIdx.x;
  const float* src; float* dst;
  if (row < LTOT){ src = mov + (size_t)row*192; dst = om + (size_t)row*192; }
  else          { src = fix + (size_t)(row-LTOT)*192; dst = of + (size_t)(row-LTOT)*192; }
  int t = threadIdx.x;
  float x0 = src[t], x1 = src[t+64], x2 = src[t+128];
  float s = x0+x1+x2, s2 = x0*x0 + x1*x1 + x2*x2;
  for (int o=32;o;o>>=1){ s += __shfl_xor(s,o); s2 += __shfl_xor(s2,o); }
  float mu = s*(1.f/192.f);
  float var = s2*(1.f/192.f) - mu*mu;
  float rs = rsqrtf(var + 1e-5f);
  dst[t]     = (x0-mu)*rs*g[t]     + b[t];
  dst[t+64]  = (x1-mu)*rs*g[t+64]  + b[t+64];
  dst[t+128] = (x2-mu)*rs*g[t+128] + b[t+128];
}

// ---------------- LayerNorm (norm2), single buffer, rows may span 2L -------
__global__ __launch_bounds__(64) void k_ln1(const float* __restrict__ x,
                                            const float* __restrict__ g, const float* __restrict__ b,
                                            float* __restrict__ y){
  int row = blockIdx.x;
  const float* src = x + (size_t)row*192;
  float* dst = y + (size_t)row*192;
  int t = threadIdx.x;
  float x0 = src[t], x1 = src[t+64], x2 = src[t+128];
  float s = x0+x1+x2, s2 = x0*x0 + x1*x1 + x2*x2;
  for (int o=32;o;o>>=1){ s += __shfl_xor(s,o); s2 += __shfl_xor(s2,o); }
  float mu = s*(1.f/192.f);
  float var = s2*(1.f/192.f) - mu*mu;
  float rs = rsqrtf(var + 1e-5f);
  dst[t]     = (x0-mu)*rs*g[t]     + b[t];
  dst[t+64]  = (x1-mu)*rs*g[t+64]  + b[t+64];
  dst[t+128] = (x2-mu)*rs*g[t+128] + b[t+128];
}

// ------ conv1 weight prep (m+f merged): f32 -> w1t[s][ch][192][8] bf16 -----
__global__ void k_prepw1b(const float* __restrict__ sm, const float* __restrict__ sf,
                          u16* __restrict__ dm, u16* __restrict__ df){
  int idx = blockIdx.x*256 + threadIdx.x;
  if (idx >= 2*192*10368) return;
  int half = idx >= 192*10368;
  int i = idx - half*192*10368;
  const float* src = half ? sf : sm;
  u16* dst = half ? df : dm;
  int swap = half ? 192 : 0;
  int c8 = i & 7;
  int t2 = i >> 3;
  int n  = t2 % 192;
  int sw = t2 / 192;
  int k  = (sw>>2)*32 + (sw&3)*8 + c8;
  int t  = k / 384; int c = k - t*384;
  int cs = c + swap; if (cs >= 384) cs -= 384;
  dst[i] = f2b(src[((size_t)n*384 + cs)*27 + t]);
}
// ------ conv2 weight prep (m+f merged): (96,192,27) -> [n][t*192+c] --------
__global__ void k_prepw2b(const float* __restrict__ sm, const float* __restrict__ sf,
                          u16* __restrict__ dm, u16* __restrict__ df){
  int idx = blockIdx.x*256 + threadIdx.x;
  if (idx >= 2*96*5184) return;
  int half = idx >= 96*5184;
  int i = idx - half*96*5184;
  const float* src = half ? sf : sm;
  u16* dst = half ? df : dm;
  int n = i / 5184; int k = i - n*5184;
  int t = k / 192; int c = k - t*192;
  dst[i] = f2b(src[((size_t)n*192 + c)*27 + t]);
}
// ------ all 8 GEMM weight copies in one launch -----------------------------
__global__ void k_prepwb8(const float* s0,const float* s1,const float* s2,const float* s3,
                          const float* s4,const float* s5,const float* s6,const float* s7,
                          u16* d0,u16* d1,u16* d2,u16* d3,u16* d4,u16* d5,u16* d6,u16* d7){
  int idx = blockIdx.x*256 + threadIdx.x;
  if      (idx < 36864)  d0[idx]        = f2b(s0[idx]);
  else if (idx < 73728)  d1[idx-36864]  = f2b(s1[idx-36864]);
  else if (idx < 147456) d2[idx-73728]  = f2b(s2[idx-73728]);
  else if (idx < 221184) d3[idx-147456] = f2b(s3[idx-147456]);
  else if (idx < 258048) d4[idx-221184] = f2b(s4[idx-221184]);
  else if (idx < 294912) d5[idx-258048] = f2b(s5[idx-258048]);
  else if (idx < 442368) d6[idx-294912] = f2b(s6[idx-294912]);
  else if (idx < 589824) d7[idx-442368] = f2b(s7[idx-442368]);
}

// ------ bias matrix prep: [type 8][head 6][key 352][query 352] f32 ---------
__global__ void k_prepbias(const float* __restrict__ rpt, float* __restrict__ bm){
  int idx = blockIdx.x*256 + threadIdx.x;
  if (idx >= 48*123904) return;
  int th = idx / 123904; int r = idx - th*123904;
  int key = r / 352; int q = r - key*352;
  int type = th / 6; int h = th - type*6;
  float v;
  if (key >= 343 || q >= 343){
    v = -30000.f;
  } else {
    int ki = key/49, kj = (key/7)%7, kk = key%7;
    int qi = q/49,   qj = (q/7)%7,   qk = q%7;
    int ridx = ((qi-ki+6)*13 + (qj-kj+6))*13 + (qk-kk+6);
    float rv = rpt[ridx*6 + h];
    int bd = (type>>2)&1, bh = (type>>1)&1, bw = type&1;
    int lq_ = (bd?((qi<4)?1:2):0)*9 + (bh?((qj<4)?1:2):0)*3 + (bw?((qk<4)?1:2):0);
    int lk_ = (bd?((ki<4)?1:2):0)*9 + (bh?((kj<4)?1:2):0)*3 + (bw?((kk<4)?1:2):0);
    v = rv + ((lq_==lk_) ? 0.f : -100.f);
  }
  bm[idx] = v;
}

// ------ padded volume builders (30^3, zero borders), bf16 ------------------
__global__ __launch_bounds__(192) void k_pad1(const float* __restrict__ m_, const float* __restrict__ f_,
                                              u16* __restrict__ xp){
  int p = blockIdx.x; int t = threadIdx.x;
  int pd = p/900; int r = p - pd*900; int ph = r/30; int pw = r - ph*30;
  int d = pd-1, h = ph-1, w = pw-1;
  u16 vm = 0, vf = 0;
  if ((unsigned)d < 28u && (unsigned)h < 28u && (unsigned)w < 28u){
    size_t l = (size_t)((d*28+h)*28+w)*192 + t;
    vm = f2b(m_[l]); vf = f2b(f_[l]);
  }
  xp[(size_t)p*384 + t] = vm;
  xp[(size_t)p*384 + 192 + t] = vf;
}
// pad2 merged m+f: grid 54000; xp2 contiguous [54000][192]
__global__ __launch_bounds__(192) void k_pad2(const float* __restrict__ t1,
                                              const float* __restrict__ sb_,
                                              u16* __restrict__ xp2){
  int p = blockIdx.x; int t = threadIdx.x;
  int half = (p >= 27000); int pl = p - half*27000;
  const float* a1 = sb_ + half*384; const float* b1 = a1 + 192;
  int pd = pl/900; int r = pl - pd*900; int ph = r/30; int pw = r - ph*30;
  int d = pd-1, h = ph-1, w = pw-1;
  u16 v = 0;
  if ((unsigned)d < 28u && (unsigned)h < 28u && (unsigned)w < 28u){
    float xv = t1[((size_t)half*LTOT + (d*28+h)*28+w)*192 + t];
    v = f2b(fmaxf(xv*a1[t] + b1[t], 0.f));
  }
  xp2[(size_t)p*192 + t] = v;
}

// ------ conv1: 2-wave blocks, wave tile 64x96, tri-buffered DMA-B ----------
// grid 686 (343 m-tiles x 2 weight halves), 128 thr.
// B: 6 DMAs/wave/step (wave wv stages chunks 2wv,2wv+1 of w1t[s][4][192][8]).
// A: reg-staged 2 x uint4 per thread. Counted vmcnt(6) + raw barrier,
// sched_barrier(0) fences (rule 18). Prefetch depth 2.
__global__ __launch_bounds__(128, 2) void k_conv1dma(const u16* __restrict__ xp,
                                                     const u16* __restrict__ wmT,
                                                     const u16* __restrict__ wfT,
                                                     float* __restrict__ outm,
                                                     float* __restrict__ outf){
  __shared__ __align__(16) u16 As[3][64*40];    // 15.4 KB
  __shared__ __align__(16) u16 Bs[3][4*1544];   // 37.1 KB
  int tid = threadIdx.x;
  // bijective XCD swizzle over nwg=686: q=85, r=6
  int b0 = blockIdx.x;
  int xcd = b0 & 7, ii = b0 >> 3;
  int bid = (xcd < 6 ? xcd*86 : 516 + (xcd-6)*85) + ii;
  int half = (bid >= 343) ? 1 : 0;
  int t = bid - half*343;
  const u16* wtb = half ? wfT : wmT;
  float* out = half ? outf : outm;
  int v0 = t*64;
  int sv  = tid>>1;                 // A staging row 0..63
  int ch2 = (tid&1)*16;             // u16 offset of this thread's 2 chunks
  int av = v0 + sv;
  int d = av/784; int rm2 = av - d*784; int hh = rm2/28; int ww = rm2 - hh*28;
  int pbase = (d*30 + hh)*30 + ww;
  int lane = tid&63, wv = tid>>6;
  int lm = lane&15, lq = lane>>4;
  int nbase = wv*96;

  float4v acc[4][6];
  #pragma unroll
  for (int mt=0; mt<4; mt++)
    #pragma unroll
    for (int nt=0; nt<6; nt++) acc[mt][nt] = (float4v)0.f;

  uint4 a_r[2];
  auto loadA = [&](int s){
    int tp = s/12, cc = s - tp*12;          // CH = 384/32 = 12
    int td = tp/9, tr = tp - td*9, th = tr/3, tw = tr - th*3;
    int toff = td*900 + th*30 + tw;
    const u16* ap = xp + (size_t)(pbase + toff)*384 + cc*32 + ch2;
    a_r[0] = *(const uint4*)(ap);
    a_r[1] = *(const uint4*)(ap + 8);
  };
  auto dmaB = [&](int buf, int s){
    #pragma unroll
    for (int c=0;c<2;c++){
      int ch = wv*2 + c;
      const u16* bsrc = wtb + ((size_t)(s*4 + ch)*192)*8 + (size_t)lane*8;
      #pragma unroll
      for (int j=0;j<3;j++)
        dma16(bsrc + j*512, &Bs[buf][ch*1544 + j*512]);
    }
  };
  auto writeA = [&](int buf){
    *(uint4*)(&As[buf][sv*40 + ch2])     = a_r[0];
    *(uint4*)(&As[buf][sv*40 + ch2 + 8]) = a_r[1];
  };

  // prologue: fill buffers 0 and 1
  loadA(0); dmaB(0, 0); writeA(0);
  loadA(1); dmaB(1, 1); writeA(1);
  asm volatile("s_waitcnt vmcnt(6) lgkmcnt(0)" ::: "memory");
  __builtin_amdgcn_sched_barrier(0);
  __builtin_amdgcn_s_barrier();
  int cur = 0;
  for (int s = 0; s < 324; s++){
    int pf = cur + 2; if (pf >= 3) pf -= 3;
    if (s < 322){ loadA(s+2); dmaB(pf, s+2); }
    short8 aa[4], bb[6];
    #pragma unroll
    for (int mt=0; mt<4; mt++)
      aa[mt] = *(const short8*)(&As[cur][(mt*16 + lm)*40 + lq*8]);
    #pragma unroll
    for (int nt=0; nt<6; nt++)
      bb[nt] = *(const short8*)(&Bs[cur][lq*1544 + (nbase + nt*16 + lm)*8]);
    #pragma unroll
    for (int nt=0; nt<6; nt++)
      #pragma unroll
      for (int mt=0; mt<4; mt++)
        acc[mt][nt] = __builtin_amdgcn_mfma_f32_16x16x32_bf16(aa[mt], bb[nt], acc[mt][nt], 0, 0, 0);
    if (s < 322){
      writeA(pf);
      asm volatile("s_waitcnt vmcnt(6) lgkmcnt(0)" ::: "memory");
      __builtin_amdgcn_sched_barrier(0);
    } else {
      asm volatile("s_waitcnt vmcnt(0) lgkmcnt(0)" ::: "memory");
      __builtin_amdgcn_sched_barrier(0);
    }
    __builtin_amdgcn_s_barrier();
    cur++; if (cur >= 3) cur = 0;
  }
  #pragma unroll
  for (int mt=0; mt<4; mt++)
    #pragma unroll
    for (int nt=0; nt<6; nt++)
      #pragma unroll
      for (int r=0; r<4; r++){
        int row = v0 + mt*16 + lq*4 + r;
        int col = nbase + nt*16 + lm;
        out[(size_t)row*192 + col] = acc[mt][nt][r];
      }
}

// ------ conv2 implicit-GEMM MFMA (verified round-2 structure) --------------
template<int CIN, int COUT>
__global__ __launch_bounds__(256, 4) void k_convmfma(const u16* __restrict__ xpA,
                                                     const u16* __restrict__ xpB,
                                                     const u16* __restrict__ wA,
                                                     const u16* __restrict__ wB,
                                                     float* __restrict__ outA,
                                                     float* __restrict__ outB){
  constexpr int K = 27*CIN;
  constexpr int CH = CIN/32;
  constexpr int STEPS = 27*CH;
  constexpr int NT = COUT/32;
  constexpr int NB8 = COUT/32;
  __shared__ __align__(16) u16 As[2][64*40];
  __shared__ __align__(16) u16 Bs[2][COUT*40];
  int tid = threadIdx.x;
  int b0 = blockIdx.x;
  int xcd = b0 & 7, ii = b0 >> 3;
  int bid = (xcd < 6 ? xcd*86 : 516 + (xcd-6)*85) + ii;
  int which = (bid >= 343) ? 1 : 0;
  int t = bid - which*343;
  const u16* xp  = which ? xpB : xpA;
  const u16* wtb = which ? wB : wA;
  float* out = which ? outB : outA;
  int v0 = t*64;
  int sv  = tid>>2;
  int c8u = (tid&3)*8;
  int av = v0 + sv;
  int d = av/784; int rm2 = av - d*784; int hh = rm2/28; int ww = rm2 - hh*28;
  int pbase = (d*30 + hh)*30 + ww;
  int lane = tid&63, wv = tid>>6;
  int lm = lane&15, lq = lane>>4;
  int mbase = (wv>>1)*32;
  int nbase = (wv&1)*(COUT/2);

  float4v acc[2][NT];
  #pragma unroll
  for (int mt=0; mt<2; mt++)
    #pragma unroll
    for (int nt=0; nt<NT; nt++) acc[mt][nt] = (float4v)0.f;

  uint4 a_r;
  uint2 b_r[NB8];
  auto load_s = [&](int s){
    int tp = s/CH, cc = s - tp*CH;
    int td = tp/9, tr = tp - td*9, th = tr/3, tw = tr - th*3;
    int toff = td*900 + th*30 + tw;
    a_r = *(const uint4*)(xp + (size_t)(pbase + toff)*CIN + cc*32 + c8u);
    #pragma unroll
    for (int j=0;j<NB8;j++){
      int bi = tid + j*256;
      int n = bi>>3, c4 = (bi&7)*4;
      b_r[j] = *(const uint2*)(wtb + (size_t)n*K + s*32 + c4);
    }
  };
  auto write_s = [&](int buf){
    *(uint4*)(&As[buf][sv*40 + c8u]) = a_r;
    #pragma unroll
    for (int j=0;j<NB8;j++){
      int bi = tid + j*256;
      int n = bi>>3, c4 = (bi&7)*4;
      *(uint2*)(&Bs[buf][n*40 + c4]) = b_r[j];
    }
  };

  load_s(0);
  write_s(0);
  __syncthreads();
  for (int s = 0; s < STEPS; s++){
    if (s+1 < STEPS) load_s(s+1);
    int buf = s&1;
    short8 aa[2], bb[NT];
    #pragma unroll
    for (int mt=0; mt<2; mt++)
      aa[mt] = *(const short8*)(&As[buf][(mbase + mt*16 + lm)*40 + lq*8]);
    #pragma unroll
    for (int nt=0; nt<NT; nt++)
      bb[nt] = *(const short8*)(&Bs[buf][(nbase + nt*16 + lm)*40 + lq*8]);
    #pragma unroll
    for (int nt=0; nt<NT; nt++)
      #pragma unroll
      for (int mt=0; mt<2; mt++)
        acc[mt][nt] = __builtin_amdgcn_mfma_f32_16x16x32_bf16(aa[mt], bb[nt], acc[mt][nt], 0, 0, 0);
    if (s+1 < STEPS) write_s((s+1)&1);
    __syncthreads();
  }
  #pragma unroll
  for (int mt=0; mt<2; mt++)
    #pragma unroll
    for (int nt=0; nt<NT; nt++)
      #pragma unroll
      for (int r=0; r<4; r++){
        int row = v0 + mbase + mt*16 + lq*4 + r;
        int col = nbase + nt*16 + lm;
        out[(size_t)row*COUT + col] = acc[mt][nt][r];
      }
}

// ---- generic MFMA GEMM; MRG=1 adds a second pointer set for the f-half ----
template<int K, int NF, int GATHER, int ASRC, int EPI, int MRG>
__global__ __launch_bounds__(256) void k_gemm(const float* __restrict__ Af,
                                              const u16* __restrict__ Ab,
                                              const u16* __restrict__ B,
                                              const float* __restrict__ bias,
                                              const float* __restrict__ resid,
                                              float* __restrict__ outf,
                                              u16* __restrict__ out16,
                                              u16* __restrict__ out16b,
                                              float scale,
                                              const u16* __restrict__ B2,
                                              const float* __restrict__ bias2,
                                              const float* __restrict__ resid2,
                                              float* __restrict__ outf2,
                                              u16* __restrict__ out162,
                                              u16* __restrict__ out16b2){
  constexpr int STEPS = K/32;
  constexpr int NB = NF/64;
  __shared__ __align__(16) u16 As[2][64*40];
  __shared__ __align__(16) u16 Bs[2][64*40];
  __shared__ int map[64];
  int tid = threadIdx.x;
  int bid = blockIdx.x;
  int mb = bid / NB, nb = bid - mb*NB;
  int v0 = mb*64, ncol0 = nb*64;
  int half = (MRG && v0 >= LTOT) ? 1 : 0;
  const u16* Bx = half ? B2 : B;
  const float* biasx = half ? bias2 : bias;
  const float* residx = half ? resid2 : resid;
  float* outfx = half ? outf2 : outf;
  u16* out16x = half ? out162 : out16;
  u16* out16bx = half ? out16b2 : out16b;
  int vloc = v0 - half*LTOT;
  if (tid < 64){
    int r = vloc + tid;
    int src;
    if (GATHER == 0){
      src = r;
    } else if (GATHER == 1){
      int w = r/343; int n = r - w*343;
      int nd = w>>4, nh = (w>>2)&3, nw = w&3;
      int i = n/49; int rr = n - i*49; int j = rr/7; int k2 = rr - j*7;
      int dd = nd*7 + i + 3; if (dd >= 28) dd -= 28;
      int hh = nh*7 + j + 3; if (hh >= 28) hh -= 28;
      int ww = nw*7 + k2 + 3; if (ww >= 28) ww -= 28;
      src = (dd*28 + hh)*28 + ww;
    } else {
      int l = r;
      int d = l/784; int rm = l - d*784; int y = rm/28; int x = rm - y*28;
      int dp = d-3; if (dp<0) dp+=28;
      int yp = y-3; if (yp<0) yp+=28;
      int xq = x-3; if (xq<0) xq+=28;
      int nd = dp/7, i = dp - nd*7;
      int nh = yp/7, j = yp - nh*7;
      int nw = xq/7, k2 = xq - nw*7;
      src = ((nd*4+nh)*4+nw)*NTOK + (i*7+j)*7 + k2;
    }
    map[tid] = src + half*LTOT;     // A is contiguous across halves
  }
  __syncthreads();
  int sv = tid>>2, c8 = (tid&3)*8;
  int arow = map[sv];
  int lane = tid&63, wv = tid>>6;
  int lm = lane&15, lq = lane>>4;
  int mbase = (wv>>1)*32, nbase = (wv&1)*32;

  float4v acc[2][2];
  #pragma unroll
  for (int mt=0; mt<2; mt++)
    #pragma unroll
    for (int nt=0; nt<2; nt++) acc[mt][nt] = (float4v)0.f;

  float4 afr0, afr1; uint4 abr; uint4 bvr;
  auto load_s = [&](int s){
    if (ASRC == 0){
      const float* ap = Af + (size_t)arow*K + s*32 + c8;
      afr0 = *(const float4*)ap;
      afr1 = *(const float4*)(ap+4);
    } else {
      abr = *(const uint4*)(Ab + (size_t)arow*K + s*32 + c8);
    }
    bvr = *(const uint4*)(Bx + (size_t)(ncol0 + sv)*K + s*32 + c8);
  };
  auto write_s = [&](int buf){
    if (ASRC == 0){
      uint4 pk;
      pk.x = (u32)f2b(afr0.x) | ((u32)f2b(afr0.y)<<16);
      pk.y = (u32)f2b(afr0.z) | ((u32)f2b(afr0.w)<<16);
      pk.z = (u32)f2b(afr1.x) | ((u32)f2b(afr1.y)<<16);
      pk.w = (u32)f2b(afr1.z) | ((u32)f2b(afr1.w)<<16);
      *(uint4*)(&As[buf][sv*40 + c8]) = pk;
    } else {
      *(uint4*)(&As[buf][sv*40 + c8]) = abr;
    }
    *(uint4*)(&Bs[buf][sv*40 + c8]) = bvr;
  };

  load_s(0);
  write_s(0);
  __syncthreads();
  for (int s = 0; s < STEPS; s++){
    if (s+1 < STEPS) load_s(s+1);
    int buf = s&1;
    short8 aa[2], bb[2];
    #pragma unroll
    for (int mt=0; mt<2; mt++)
      aa[mt] = *(const short8*)(&As[buf][(mbase + mt*16 + lm)*40 + lq*8]);
    #pragma unroll
    for (int nt=0; nt<2; nt++)
      bb[nt] = *(const short8*)(&Bs[buf][(nbase + nt*16 + lm)*40 + lq*8]);
    #pragma unroll
    for (int nt=0; nt<2; nt++)
      #pragma unroll
      for (int mt=0; mt<2; mt++)
        acc[mt][nt] = __builtin_amdgcn_mfma_f32_16x16x32_bf16(aa[mt], bb[nt], acc[mt][nt], 0, 0, 0);
    if (s+1 < STEPS) write_s((s+1)&1);
    __syncthreads();
  }
  // epilogue
  float bv[2];
  #pragma unroll
  for (int nt=0; nt<2; nt++) bv[nt] = biasx ? biasx[ncol0 + nbase + nt*16 + lm] : 0.f;
  #pragma unroll
  for (int mt=0; mt<2; mt++){
    #pragma unroll
    for (int r=0; r<4; r++){
      int row = v0 + mbase + mt*16 + lq*4 + r;
      int rowl = row - half*LTOT;
      if (EPI == 0 || EPI == 3){
        int w = rowl/343; int tok = rowl - w*343;
        #pragma unroll
        for (int nt=0; nt<2; nt++){
          int col = ncol0 + nbase + nt*16 + lm;
          float val = (acc[mt][nt][r] + bv[nt]) * scale;
          if (EPI == 0){
            int h = col>>5, c = col&31;
            out16x[((size_t)(w*6 + h)*343 + tok)*32 + c] = f2b(val);
          } else {
            u16* dst = (col < 192) ? out16x : out16bx;
            int cc = (col < 192) ? col : col - 192;
            int h = cc>>5, c = cc&31;
            dst[((size_t)(w*6 + h)*343 + tok)*32 + c] = f2b(val);
          }
        }
      } else if (EPI == 1){
        #pragma unroll
        for (int nt=0; nt<2; nt++){
          int col = ncol0 + nbase + nt*16 + lm;
          size_t o = (size_t)rowl*NF + col;
          outfx[o] = acc[mt][nt][r] + bv[nt] + residx[o];
        }
      } else {
        #pragma unroll
        for (int nt=0; nt<2; nt++){
          int col = ncol0 + nbase + nt*16 + lm;
          float v = acc[mt][nt][r] + bv[nt];
          float gl = 0.5f*v*(1.f + erff(v*0.70710678118f));
          out16[(size_t)row*NF + col] = f2b(gl);   // fc1: single global hs
        }
      }
    }
  }
}

// ---- BN stats, merged m+f: grid 128, x = contiguous [2L][C] ---------------
__global__ __launch_bounds__(192) void k_bnsum(const float* __restrict__ x, int C,
                                               float* __restrict__ psum){
  int bid = blockIdx.x, t = threadIdx.x;
  int rpi = 192/C;
  int c  = (C==192) ? t : (t % 96);
  int ro = (C==192) ? 0 : (t / 96);
  float s=0.f, s2=0.f;
  int base = bid*343;
  for (int r = ro; r < 343; r += rpi){
    float v = x[(size_t)(base+r)*C + c];
    s += v; s2 += v*v;
  }
  psum[(size_t)bid*384 + t]       = s;
  psum[(size_t)bid*384 + 192 + t] = s2;
}
__global__ void k_bnfin2(const float* __restrict__ psum, int C,
                         const float* __restrict__ g0, const float* __restrict__ bb0,
                         const float* __restrict__ g1, const float* __restrict__ bb1,
                         float* a0, float* b0o, float* a1, float* b1o){
  int h = blockIdx.x;
  int c = threadIdx.x;
  if (c >= C) return;
  const float* g  = h ? g1 : g0;
  const float* bb = h ? bb1 : bb0;
  float* ao = h ? a1 : a0;
  float* bo = h ? b1o : b0o;
  const float* ps = psum + (size_t)h*64*384;
  int slots = 192/C;
  float s=0.f, s2=0.f;
  for (int b=0; b<64; b++)
    for (int k=0; k<slots; k++){
      s  += ps[(size_t)b*384 + k*C + c];
      s2 += ps[(size_t)b*384 + 192 + k*C + c];
    }
  float mu = s/(float)LTOT;
  float var = s2/(float)LTOT - mu*mu;
  float rstd = rsqrtf(var + 1e-5f);
  float aa = rstd * g[c];
  ao[c] = aa;
  bo[c] = bb[c] - mu*aa;
}

// ------------- conv3 1x1x1 merged m+f: grid 2L -----------------------------
__global__ __launch_bounds__(96) void k_flow(const float* __restrict__ t2,
                                             const float* __restrict__ a2b,
                                             const float* __restrict__ w3m,
                                             const float* __restrict__ w3f,
                                             float* __restrict__ flow){
  __shared__ float xr[96];
  int l = blockIdx.x; int t = threadIdx.x;
  int half = l >= LTOT; int ll = l - half*LTOT;
  const float* a2 = a2b + half*192; const float* b2 = a2 + 96;
  const float* w3 = half ? w3f : w3m;
  float xv = t2[(size_t)l*96 + t];
  xr[t] = fmaxf(xv*a2[t] + b2[t], 0.f);
  __syncthreads();
  if (t < 18){
    float acc = 0.f;
    for (int c=0;c<96;c++) acc += xr[c]*w3[t*96 + c];
    flow[((size_t)half*18 + t)*LTOT + ll] = acc;
  }
}

// ------------- trilinear warp merged m+f: grid 2L --------------------------
__global__ __launch_bounds__(192) void k_warp(const float* __restrict__ src,
                                              const float* __restrict__ flow, float* __restrict__ dst){
  int l = blockIdx.x; int tid = threadIdx.x; int hh = tid>>5;
  int half = l >= LTOT; int ll = l - half*LTOT;
  const float* s_ = src + (size_t)half*LTOT*192;
  int d = ll/784; int rm = ll - d*784; int y = rm/28; int x = rm - y*28;
  float fd = flow[((size_t)half*18 + hh*3+0)*LTOT + ll];
  float fy = flow[((size_t)half*18 + hh*3+1)*LTOT + ll];
  float fx = flow[((size_t)half*18 + hh*3+2)*LTOT + ll];
  float cd = fminf(fmaxf((float)d + fd, 0.f), 27.f);
  float cy = fminf(fmaxf((float)y + fy, 0.f), 27.f);
  float cx = fminf(fmaxf((float)x + fx, 0.f), 27.f);
  int d0 = (int)floorf(cd); int d1 = min(d0+1, 27);
  int y0 = (int)floorf(cy); int y1 = min(y0+1, 27);
  int x0 = (int)floorf(cx); int x1 = min(x0+1, 27);
  float wd = cd - (float)d0, wy = cy - (float)y0, wx = cx - (float)x0;
  #define SMP(di,yi,xi) s_[(size_t)(((di)*28+(yi))*28+(xi))*192 + tid]
  float v000 = SMP(d0,y0,x0), v001 = SMP(d0,y0,x1), v010 = SMP(d0,y1,x0), v011 = SMP(d0,y1,x1);
  float v100 = SMP(d1,y0,x0), v101 = SMP(d1,y0,x1), v110 = SMP(d1,y1,x0), v111 = SMP(d1,y1,x1);
  #undef SMP
  float o = v000*(1-wd)*(1-wy)*(1-wx) + v001*(1-wd)*(1-wy)*wx
          + v010*(1-wd)*wy*(1-wx)     + v011*(1-wd)*wy*wx
          + v100*wd*(1-wy)*(1-wx)     + v101*wd*(1-wy)*wx
          + v110*wd*wy*(1-wx)         + v111*wd*wy*wx;
  dst[(size_t)l*192 + tid] = o;
}

// ------------ MFMA attention merged (both directions): grid 4608 -----------
__global__ __launch_bounds__(256) void k_attmfma(const u16* __restrict__ Q1,
                                                 const u16* __restrict__ K1,
                                                 const u16* __restrict__ V1,
                                                 const u16* __restrict__ Q2,
                                                 const u16* __restrict__ K2,
                                                 const u16* __restrict__ V2,
                                                 const float* __restrict__ bm,
                                                 float* __restrict__ ctx1,
                                                 float* __restrict__ ctx2){
  __shared__ __align__(16) u16 Kl[352*40];      // [key][40]
  __shared__ __align__(16) u16 Vt[32*360];      // [dim][360]
  __shared__ __align__(16) u16 Pl[4][2][16*40]; // per-wave, dbuf
  int bid0 = blockIdx.x;
  int halfsel = bid0 >= 2304;
  int bid = bid0 - halfsel*2304;
  const u16* Q = halfsel ? Q2 : Q1;
  const u16* K = halfsel ? K2 : K1;
  const u16* V = halfsel ? V2 : V1;
  float* ctx = halfsel ? ctx2 : ctx1;
  int wh = bid/6, qg = bid - (bid/6)*6;
  int w = wh/6, h = wh - w*6;
  int tid = threadIdx.x;
  int nd = w>>4, nh = (w>>2)&3, nw = w&3;
  int type = ((nd==3)?4:0) | ((nh==3)?2:0) | ((nw==3)?1:0);
  const u16* kb = K + (size_t)wh*10976;
  const u16* vbp = V + (size_t)wh*10976;
  for (int idx=tid; idx<343*4; idx+=256){
    int row = idx>>2, c8 = (idx&3)*8;
    uint4 val = *(const uint4*)(kb + row*32 + c8);
    *(uint4*)(&Kl[row*40 + c8]) = val;
  }
  for (int idx=tid; idx<9*40; idx+=256) Kl[343*40 + idx] = 0;
  for (int idx=tid; idx<343*4; idx+=256){
    int row = idx>>2, c8 = (idx&3)*8;
    uint4 val = *(const uint4*)(vbp + row*32 + c8);
    const u16* pv = (const u16*)&val;
    #pragma unroll
    for (int j=0;j<8;j++) Vt[(c8+j)*360 + row] = pv[j];
  }
  for (int idx=tid; idx<32*17; idx+=256){
    int dd = idx/17, cc = 343 + idx - (idx/17)*17;
    Vt[dd*360 + cc] = 0;
  }
  __syncthreads();
  int lane = tid&63, wv = tid>>6;
  int lm = lane&15, lq = lane>>4;
  const float* bmh = bm + (size_t)(type*6 + h)*123904;
  int qt = qg*4 + wv;
  if (qt < 22){
    int q0 = qt*16;
    short8 bq = *(const short8*)(Q + (size_t)wh*10976 + (q0+lm)*32 + lq*8);
    float4v sc[22];
    #pragma unroll
    for (int kt=0; kt<22; kt++){
      short8 ak = *(const short8*)(&Kl[(kt*16+lm)*40 + lq*8]);
      sc[kt] = __builtin_amdgcn_mfma_f32_16x16x32_bf16(ak, bq, (float4v)0.f, 0, 0, 0);
    }
    const float* bcol = bmh + q0 + lm;
    float mx = -3.0e38f;
    #pragma unroll
    for (int kt=0; kt<22; kt++){
      #pragma unroll
      for (int r=0; r<4; r++){
        int key = kt*16 + lq*4 + r;
        float s = sc[kt][r] + bcol[(size_t)key*352];
        sc[kt][r] = s;
        mx = fmaxf(mx, s);
      }
    }
    mx = fmaxf(mx, __shfl_xor(mx, 16));
    mx = fmaxf(mx, __shfl_xor(mx, 32));
    float sm = 0.f;
    #pragma unroll
    for (int kt=0; kt<22; kt++){
      #pragma unroll
      for (int r=0; r<4; r++){
        float p = __expf(sc[kt][r] - mx);
        sc[kt][r] = p;
        sm += p;
      }
    }
    sm += __shfl_xor(sm, 16);
    sm += __shfl_xor(sm, 32);
    float inv = 1.f/sm;
    float4v o0 = (float4v)0.f, o1 = (float4v)0.f;
    #pragma unroll
    for (int s=0; s<11; s++){
      u16* pw = &Pl[wv][s&1][0];
      #pragma unroll
      for (int hf=0; hf<2; hf++){
        int kt = 2*s + hf;
        uint2 pv2;
        pv2.x = (u32)f2b(sc[kt][0]) | ((u32)f2b(sc[kt][1])<<16);
        pv2.y = (u32)f2b(sc[kt][2]) | ((u32)f2b(sc[kt][3])<<16);
        *(uint2*)(&pw[lm*40 + hf*16 + lq*4]) = pv2;
      }
      short8 bp = *(const short8*)(&pw[lm*40 + lq*8]);
      short8 a0 = *(const short8*)(&Vt[lm*360 + s*32 + lq*8]);
      short8 a1 = *(const short8*)(&Vt[(16+lm)*360 + s*32 + lq*8]);
      o0 = __builtin_amdgcn_mfma_f32_16x16x32_bf16(a0, bp, o0, 0, 0, 0);
      o1 = __builtin_amdgcn_mfma_f32_16x16x32_bf16(a1, bp, o1, 0, 0, 0);
    }
    int query = q0 + lm;
    if (query < 343){
      float* ob = ctx + ((size_t)w*NTOK + query)*192 + h*32;
      float4 t0, t1v;
      t0.x = o0[0]*inv; t0.y = o0[1]*inv; t0.z = o0[2]*inv; t0.w = o0[3]*inv;
      t1v.x = o1[0]*inv; t1v.y = o1[1]*inv; t1v.z = o1[2]*inv; t1v.w = o1[3]*inv;
      *(float4*)(ob + lq*4) = t0;
      *(float4*)(ob + 16 + lq*4) = t1v;
    }
  }
}

// ===========================================================================
extern "C" void kernel_launch(void* const* d_in, const int* in_sizes, int n_in,
                              void* d_out, int out_size, void* d_ws, size_t ws_size,
                              hipStream_t stream){
  const float* mov     = (const float*)d_in[0];
  const float* fix     = (const float*)d_in[1];
  const float* n1g     = (const float*)d_in[2];
  const float* n1b     = (const float*)d_in[3];
  const float* offm_w1 = (const float*)d_in[4];
  const float* offm_g1 = (const float*)d_in[5];
  const float* offm_b1 = (const float*)d_in[6];
  const float* offm_w2 = (const float*)d_in[7];
  const float* offm_g2 = (const float*)d_in[8];
  const float* offm_b2 = (const float*)d_in[9];
  const float* offm_w3 = (const float*)d_in[10];
  const float* offf_w1 = (const float*)d_in[11];
  const float* offf_g1 = (const float*)d_in[12];
  const float* offf_b1 = (const float*)d_in[13];
  const float* offf_w2 = (const float*)d_in[14];
  const float* offf_g2 = (const float*)d_in[15];
  const float* offf_b2 = (const float*)d_in[16];
  const float* offf_w3 = (const float*)d_in[17];
  const float* mq_w    = (const float*)d_in[18];
  const float* mkv_w   = (const float*)d_in[19];
  const float* fq_w    = (const float*)d_in[20];
  const float* fkv_w   = (const float*)d_in[21];
  const float* mproj_w = (const float*)d_in[22];
  const float* fproj_w = (const float*)d_in[23];
  const float* mq_b    = (const float*)d_in[24];
  const float* mkv_b   = (const float*)d_in[25];
  const float* fq_b    = (const float*)d_in[26];
  const float* fkv_b   = (const float*)d_in[27];
  const float* mproj_b = (const float*)d_in[28];
  const float* fproj_b = (const float*)d_in[29];
  const float* rpbt    = (const float*)d_in[30];
  const float* n2g     = (const float*)d_in[31];
  const float* n2b     = (const float*)d_in[32];
  const float* fc1_w   = (const float*)d_in[33];
  const float* fc1_b   = (const float*)d_in[34];
  const float* fc2_w   = (const float*)d_in[35];
  const float* fc2_b   = (const float*)d_in[36];
  float* outp = (float*)d_out;

  float* W = (float*)d_ws;
  const size_t L192 = (size_t)LTOT*192;   // floats per region (16.86 MB)
  // conv-phase layout:
  float* m_   = W;                         // region 0
  float* f_   = W + 1*L192;                // region 1
  float* t1   = W + 2*L192;                // regions 2,3 ([2L][192])
  u16* xp     = (u16*)(W + 4*L192);        // 27000*384 u16
  u16* xp2    = xp + (size_t)27000*384;    // 54000*192 u16, contiguous m|f
  float* sb   = W + 6*L192 + 3000000;      // stats block
  float* a1m = sb,       *b1m = sb+192;
  float* a1f = sb+384,   *b1f = sb+576;
  float* a2m = sb+768,   *b2m = sb+864;
  float* a2f = sb+960,   *b2f = sb+1056;
  float* psum = sb + 1536;                 // 128*384 floats
  float* flowm = W + 6*L192 + 3100000;     // [36][LTOT]
  float* t2   = W + 7*L192;                // [2L][96]
  u16* wt1m = (u16*)(W + 8*L192);          // conv weights, region 8
  u16* wt1f = wt1m + 192*10368;
  u16* wt2m = wt1f + 192*10368;
  u16* wt2f = wt2m + 96*5184;
  // post-conv reuse:
  float* dmov = W + 4*L192;                // region 4
  float* dfix = W + 5*L192;                // region 5
  float* ctxm = dmov; float* ctxf = dfix;
  float* mout = m_;   float* fout = f_;
  u16* QMb = (u16*)(W + 6*L192);
  u16* QFb = (u16*)(W + 7*L192);
  u16* Kmb = (u16*)(W + 2*L192);
  u16* Vmb = (u16*)(W + 3*L192);
  u16* Kfb = (u16*)(W + 8*L192);
  u16* Vfb = (u16*)(W + 9*L192);
  float* bm = W;
  u16* wq_m  = (u16*)(W + 9*L192) + 4214784;
  u16* wq_f  = wq_m  + 36864;
  u16* wkv_m = wq_f  + 36864;
  u16* wkv_f = wkv_m + 73728;
  u16* wpj_m = wkv_f + 73728;
  u16* wpj_f = wpj_m + 36864;
  u16* wfc1  = wpj_f + 36864;
  u16* wfc2  = wfc1  + 147456;
  u16* hs16  = (u16*)(W + 2*L192);         // [2L][768] regions 2-5
  float* lnbuf = W + 6*L192;               // [2L][192] regions 6,7

  // weight prep (3 launches)
  k_prepw1b<<<(2*192*10368+255)/256, 256, 0, stream>>>(offm_w1, offf_w1, wt1m, wt1f);
  k_prepw2b<<<(2*96*5184+255)/256, 256, 0, stream>>>(offm_w2, offf_w2, wt2m, wt2f);
  k_prepwb8<<<2304, 256, 0, stream>>>(mq_w, fq_w, mkv_w, fkv_w, mproj_w, fproj_w, fc1_w, fc2_w,
                                      wq_m, wq_f, wkv_m, wkv_f, wpj_m, wpj_f, wfc1, wfc2);
  // layernorm1
  k_ln<<<2*LTOT, 64, 0, stream>>>(mov, fix, n1g, n1b, m_, f_);
  // padded bf16 volume [m|f]
  k_pad1<<<27000, 192, 0, stream>>>(m_, f_, xp);
  // conv1 (2-wave 64x96 tiles, tri-buffered, counted vmcnt)
  k_conv1dma<<<686, 128, 0, stream>>>(xp, wt1m, wt1f, t1, t1 + 2*L192);
  k_bnsum<<<128, 192, 0, stream>>>(t1, 192, psum);
  k_bnfin2<<<2, 192, 0, stream>>>(psum, 192, offm_g1, offm_b1, offf_g1, offf_b1, a1m, b1m, a1f, b1f);
  k_pad2<<<54000, 192, 0, stream>>>(t1, sb, xp2);
  // conv2 (m+f halves of contiguous xp2)
  k_convmfma<192,96><<<686, 256, 0, stream>>>(xp2, xp2 + (size_t)27000*192, wt2m, wt2f,
                                              t2, t2 + (size_t)LTOT*96);
  k_bnsum<<<128, 192, 0, stream>>>(t2, 96, psum);
  k_bnfin2<<<2, 96, 0, stream>>>(psum, 96, offm_g2, offm_b2, offf_g2, offf_b2, a2m, b2m, a2f, b2f);
  k_flow<<<2*LTOT, 96, 0, stream>>>(t2, sb+768, offm_w3, offf_w3, flowm);
  // deformable warp (merged)
  k_warp<<<2*LTOT, 192, 0, stream>>>(m_, flowm, dmov);
  // windowed projections (merged m+f)
  const float scale = 0.17677669529663687f; // 32^-0.5
  k_gemm<192,192,1,0,0,1><<<2*343*3, 256, 0, stream>>>(dmov, nullptr, wq_m, mq_b, nullptr, nullptr, QMb, nullptr, scale,
                                                       wq_f, fq_b, nullptr, nullptr, QFb, nullptr);
  k_gemm<192,384,1,0,3,1><<<2*343*6, 256, 0, stream>>>(m_, nullptr, wkv_m, mkv_b, nullptr, nullptr, Kmb, Vmb, 1.f,
                                                       wkv_f, fkv_b, nullptr, nullptr, Kfb, Vfb);
  // bias matrix (m_/f_ now dead)
  k_prepbias<<<(48*123904+255)/256, 256, 0, stream>>>(rpbt, bm);
  // attention merged: mo = attend(dfQ, mK, mV); fo = attend(dmQ, fK, fV)
  k_attmfma<<<4608, 256, 0, stream>>>(QFb, Kmb, Vmb, QMb, Kfb, Vfb, bm, ctxm, ctxf);
  // proj + residual + window-reverse (merged)
  k_gemm<192,192,2,0,1,1><<<2*343*3, 256, 0, stream>>>(ctxm, nullptr, wpj_m, mproj_b, mov, mout, nullptr, nullptr, 1.f,
                                                       wpj_f, fproj_b, fix, fout, nullptr, nullptr);
  // MLP both halves (contiguous rows)
  k_ln1<<<2*LTOT, 64, 0, stream>>>(mout, n2g, n2b, lnbuf);
  k_gemm<192,768,0,0,2,0><<<2*343*12, 256, 0, stream>>>(lnbuf, nullptr, wfc1, fc1_b, nullptr, nullptr, hs16, nullptr, 1.f,
                                                        nullptr, nullptr, nullptr, nullptr, nullptr, nullptr);
  k_gemm<768,192,0,1,1,0><<<2*343*3, 256, 0, stream>>>(nullptr, hs16, wfc2, fc2_b, mout, outp, nullptr, nullptr, 1.f,
                                                       nullptr, nullptr, nullptr, nullptr, nullptr, nullptr);
}

// Round 9
// 1214.325 us; speedup vs baseline: 1.1284x; 1.1284x over previous
//
#include <hip/hip_runtime.h>

#define LTOT 21952      // 28^3
#define NTOK 343        // 7^3

typedef unsigned short u16;
typedef unsigned int   u32;
typedef __attribute__((ext_vector_type(8))) short short8;
typedef __attribute__((ext_vector_type(4))) float float4v;

__device__ __forceinline__ u16 f2b(float f){
  u32 x = __float_as_uint(f);
  u32 r = (x + 0x7fffu + ((x>>16)&1u)) >> 16;
  return (u16)r;
}

// 16B global -> LDS direct DMA (HW dest = wave-uniform base + lane*16)
__device__ __forceinline__ void dma16(const u16* g, u16* l){
  __builtin_amdgcn_global_load_lds((const __attribute__((address_space(1))) u32*)g,
                                   (__attribute__((address_space(3))) u32*)l,
                                   16, 0, 0);
}

// ---------------- LayerNorm (norm1) : f32 in -> f32 out --------------------
__global__ __launch_bounds__(64) void k_ln(const float* __restrict__ mov, const float* __restrict__ fix,
                                           const float* __restrict__ g, const float* __restrict__ b,
                                           float* __restrict__ om, float* __restrict__ of){
  int row = blockIdx.x;
  const float* src; float* dst;
  if (row < LTOT){ src = mov + (size_t)row*192; dst = om + (size_t)row*192; }
  else          { src = fix + (size_t)(row-LTOT)*192; dst = of + (size_t)(row-LTOT)*192; }
  int t = threadIdx.x;
  float x0 = src[t], x1 = src[t+64], x2 = src[t+128];
  float s = x0+x1+x2, s2 = x0*x0 + x1*x1 + x2*x2;
  for (int o=32;o;o>>=1){ s += __shfl_xor(s,o); s2 += __shfl_xor(s2,o); }
  float mu = s*(1.f/192.f);
  float var = s2*(1.f/192.f) - mu*mu;
  float rs = rsqrtf(var + 1e-5f);
  dst[t]     = (x0-mu)*rs*g[t]     + b[t];
  dst[t+64]  = (x1-mu)*rs*g[t+64]  + b[t+64];
  dst[t+128] = (x2-mu)*rs*g[t+128] + b[t+128];
}

// ---------------- LayerNorm (norm2), single buffer, rows may span 2L -------
__global__ __launch_bounds__(64) void k_ln1(const float* __restrict__ x,
                                            const float* __restrict__ g, const float* __restrict__ b,
                                            float* __restrict__ y){
  int row = blockIdx.x;
  const float* src = x + (size_t)row*192;
  float* dst = y + (size_t)row*192;
  int t = threadIdx.x;
  float x0 = src[t], x1 = src[t+64], x2 = src[t+128];
  float s = x0+x1+x2, s2 = x0*x0 + x1*x1 + x2*x2;
  for (int o=32;o;o>>=1){ s += __shfl_xor(s,o); s2 += __shfl_xor(s2,o); }
  float mu = s*(1.f/192.f);
  float var = s2*(1.f/192.f) - mu*mu;
  float rs = rsqrtf(var + 1e-5f);
  dst[t]     = (x0-mu)*rs*g[t]     + b[t];
  dst[t+64]  = (x1-mu)*rs*g[t+64]  + b[t+64];
  dst[t+128] = (x2-mu)*rs*g[t+128] + b[t+128];
}

// ------ conv1 weight prep (m+f merged): f32 -> w1t[s][wv][192][8] bf16 -----
__global__ void k_prepw1b(const float* __restrict__ sm, const float* __restrict__ sf,
                          u16* __restrict__ dm, u16* __restrict__ df){
  int idx = blockIdx.x*256 + threadIdx.x;
  if (idx >= 2*192*10368) return;
  int half = idx >= 192*10368;
  int i = idx - half*192*10368;
  const float* src = half ? sf : sm;
  u16* dst = half ? df : dm;
  int swap = half ? 192 : 0;
  int c8 = i & 7;
  int t2 = i >> 3;
  int n  = t2 % 192;
  int sw = t2 / 192;
  int k  = (sw>>2)*32 + (sw&3)*8 + c8;
  int t  = k / 384; int c = k - t*384;
  int cs = c + swap; if (cs >= 384) cs -= 384;
  dst[i] = f2b(src[((size_t)n*384 + cs)*27 + t]);
}
// ------ conv2 weight prep (m+f merged): (96,192,27) -> [n][t*192+c] --------
__global__ void k_prepw2b(const float* __restrict__ sm, const float* __restrict__ sf,
                          u16* __restrict__ dm, u16* __restrict__ df){
  int idx = blockIdx.x*256 + threadIdx.x;
  if (idx >= 2*96*5184) return;
  int half = idx >= 96*5184;
  int i = idx - half*96*5184;
  const float* src = half ? sf : sm;
  u16* dst = half ? df : dm;
  int n = i / 5184; int k = i - n*5184;
  int t = k / 192; int c = k - t*192;
  dst[i] = f2b(src[((size_t)n*192 + c)*27 + t]);
}
// ------ all 8 GEMM weight copies in one launch -----------------------------
__global__ void k_prepwb8(const float* s0,const float* s1,const float* s2,const float* s3,
                          const float* s4,const float* s5,const float* s6,const float* s7,
                          u16* d0,u16* d1,u16* d2,u16* d3,u16* d4,u16* d5,u16* d6,u16* d7){
  int idx = blockIdx.x*256 + threadIdx.x;
  if      (idx < 36864)  d0[idx]        = f2b(s0[idx]);
  else if (idx < 73728)  d1[idx-36864]  = f2b(s1[idx-36864]);
  else if (idx < 147456) d2[idx-73728]  = f2b(s2[idx-73728]);
  else if (idx < 221184) d3[idx-147456] = f2b(s3[idx-147456]);
  else if (idx < 258048) d4[idx-221184] = f2b(s4[idx-221184]);
  else if (idx < 294912) d5[idx-258048] = f2b(s5[idx-258048]);
  else if (idx < 442368) d6[idx-294912] = f2b(s6[idx-294912]);
  else if (idx < 589824) d7[idx-442368] = f2b(s7[idx-442368]);
}

// ------ bias matrix prep: [type 8][head 6][key 352][query 352] f32 ---------
__global__ void k_prepbias(const float* __restrict__ rpt, float* __restrict__ bm){
  int idx = blockIdx.x*256 + threadIdx.x;
  if (idx >= 48*123904) return;
  int th = idx / 123904; int r = idx - th*123904;
  int key = r / 352; int q = r - key*352;
  int type = th / 6; int h = th - type*6;
  float v;
  if (key >= 343 || q >= 343){
    v = -30000.f;
  } else {
    int ki = key/49, kj = (key/7)%7, kk = key%7;
    int qi = q/49,   qj = (q/7)%7,   qk = q%7;
    int ridx = ((qi-ki+6)*13 + (qj-kj+6))*13 + (qk-kk+6);
    float rv = rpt[ridx*6 + h];
    int bd = (type>>2)&1, bh = (type>>1)&1, bw = type&1;
    int lq_ = (bd?((qi<4)?1:2):0)*9 + (bh?((qj<4)?1:2):0)*3 + (bw?((qk<4)?1:2):0);
    int lk_ = (bd?((ki<4)?1:2):0)*9 + (bh?((kj<4)?1:2):0)*3 + (bw?((kk<4)?1:2):0);
    v = rv + ((lq_==lk_) ? 0.f : -100.f);
  }
  bm[idx] = v;
}

// ------ padded volume builders (30^3, zero borders), bf16 ------------------
__global__ __launch_bounds__(192) void k_pad1(const float* __restrict__ m_, const float* __restrict__ f_,
                                              u16* __restrict__ xp){
  int p = blockIdx.x; int t = threadIdx.x;
  int pd = p/900; int r = p - pd*900; int ph = r/30; int pw = r - ph*30;
  int d = pd-1, h = ph-1, w = pw-1;
  u16 vm = 0, vf = 0;
  if ((unsigned)d < 28u && (unsigned)h < 28u && (unsigned)w < 28u){
    size_t l = (size_t)((d*28+h)*28+w)*192 + t;
    vm = f2b(m_[l]); vf = f2b(f_[l]);
  }
  xp[(size_t)p*384 + t] = vm;
  xp[(size_t)p*384 + 192 + t] = vf;
}
// pad2 merged m+f: grid 54000; xp2 contiguous [54000][192]
__global__ __launch_bounds__(192) void k_pad2(const float* __restrict__ t1,
                                              const float* __restrict__ sb_,
                                              u16* __restrict__ xp2){
  int p = blockIdx.x; int t = threadIdx.x;
  int half = (p >= 27000); int pl = p - half*27000;
  const float* a1 = sb_ + half*384; const float* b1 = a1 + 192;
  int pd = pl/900; int r = pl - pd*900; int ph = r/30; int pw = r - ph*30;
  int d = pd-1, h = ph-1, w = pw-1;
  u16 v = 0;
  if ((unsigned)d < 28u && (unsigned)h < 28u && (unsigned)w < 28u){
    float xv = t1[((size_t)half*LTOT + (d*28+h)*28+w)*192 + t];
    v = f2b(fmaxf(xv*a1[t] + b1[t], 0.f));
  }
  xp2[(size_t)p*192 + t] = v;
}

// ------ conv1: tri-buffered DMA-B / reg-A, counted vmcnt + raw barrier -----
// grid 686 (343 m-tiles x 2 weight halves), 256 thr, 4 waves of 64x48.
// Prefetch depth 2: at each barrier only the newest 3 B-DMAs stay in flight.
// Rule-18 fences: sched_barrier(0) after each inline-asm waitcnt.
// [r7 WINNER config: 312us, 3 blocks/CU resident, MfmaUtil 24%]
__global__ __launch_bounds__(256, 3) void k_conv1dma(const u16* __restrict__ xp,
                                                     const u16* __restrict__ wmT,
                                                     const u16* __restrict__ wfT,
                                                     float* __restrict__ outm,
                                                     float* __restrict__ outf){
  __shared__ __align__(16) u16 As[3][64*40];    // 15.4 KB
  __shared__ __align__(16) u16 Bs[3][4*1544];   // 37.1 KB
  int tid = threadIdx.x;
  // bijective XCD swizzle over nwg=686: q=85, r=6
  int b0 = blockIdx.x;
  int xcd = b0 & 7, ii = b0 >> 3;
  int bid = (xcd < 6 ? xcd*86 : 516 + (xcd-6)*85) + ii;
  int half = (bid >= 343) ? 1 : 0;
  int t = bid - half*343;
  const u16* wtb = half ? wfT : wmT;
  float* out = half ? outf : outm;
  int v0 = t*64;
  int sv  = tid>>2;                 // A staging row
  int c8u = (tid&3)*8;
  int av = v0 + sv;
  int d = av/784; int rm2 = av - d*784; int hh = rm2/28; int ww = rm2 - hh*28;
  int pbase = (d*30 + hh)*30 + ww;
  int lane = tid&63, wv = tid>>6;
  int lm = lane&15, lq = lane>>4;
  int nbase = wv*48;

  float4v acc[4][3];
  #pragma unroll
  for (int mt=0; mt<4; mt++)
    #pragma unroll
    for (int nt=0; nt<3; nt++) acc[mt][nt] = (float4v)0.f;

  uint4 a_r;
  auto loadA = [&](int s){
    int tp = s/12, cc = s - tp*12;          // CH = 384/32 = 12
    int td = tp/9, tr = tp - td*9, th = tr/3, tw = tr - th*3;
    int toff = td*900 + th*30 + tw;
    a_r = *(const uint4*)(xp + (size_t)(pbase + toff)*384 + cc*32 + c8u);
  };
  auto dmaB = [&](int buf, int s){
    const u16* bsrc = wtb + ((size_t)(s*4 + wv)*192)*8 + (size_t)lane*8;
    #pragma unroll
    for (int j=0;j<3;j++)
      dma16(bsrc + j*512, &Bs[buf][wv*1544 + j*512]);
  };
  auto writeA = [&](int buf){
    *(uint4*)(&As[buf][sv*40 + c8u]) = a_r;
  };

  // prologue: fill buffers 0 and 1
  loadA(0); dmaB(0, 0); writeA(0);
  loadA(1); dmaB(1, 1); writeA(1);
  asm volatile("s_waitcnt vmcnt(3) lgkmcnt(0)" ::: "memory");
  __builtin_amdgcn_sched_barrier(0);
  __builtin_amdgcn_s_barrier();
  int cur = 0;
  for (int s = 0; s < 324; s++){
    int pf = cur + 2; if (pf >= 3) pf -= 3;
    if (s < 322){ loadA(s+2); dmaB(pf, s+2); }
    short8 aa[4], bb[3];
    #pragma unroll
    for (int mt=0; mt<4; mt++)
      aa[mt] = *(const short8*)(&As[cur][(mt*16 + lm)*40 + lq*8]);
    #pragma unroll
    for (int nt=0; nt<3; nt++)
      bb[nt] = *(const short8*)(&Bs[cur][lq*1544 + (nbase + nt*16 + lm)*8]);
    #pragma unroll
    for (int nt=0; nt<3; nt++)
      #pragma unroll
      for (int mt=0; mt<4; mt++)
        acc[mt][nt] = __builtin_amdgcn_mfma_f32_16x16x32_bf16(aa[mt], bb[nt], acc[mt][nt], 0, 0, 0);
    if (s < 322){
      writeA(pf);
      asm volatile("s_waitcnt vmcnt(3) lgkmcnt(0)" ::: "memory");
      __builtin_amdgcn_sched_barrier(0);
    } else {
      asm volatile("s_waitcnt vmcnt(0) lgkmcnt(0)" ::: "memory");
      __builtin_amdgcn_sched_barrier(0);
    }
    __builtin_amdgcn_s_barrier();
    cur++; if (cur >= 3) cur = 0;
  }
  #pragma unroll
  for (int mt=0; mt<4; mt++)
    #pragma unroll
    for (int nt=0; nt<3; nt++)
      #pragma unroll
      for (int r=0; r<4; r++){
        int row = v0 + mt*16 + lq*4 + r;
        int col = nbase + nt*16 + lm;
        out[(size_t)row*192 + col] = acc[mt][nt][r];
      }
}

// ------ conv2 implicit-GEMM MFMA (verified round-2 structure) --------------
template<int CIN, int COUT>
__global__ __launch_bounds__(256, 4) void k_convmfma(const u16* __restrict__ xpA,
                                                     const u16* __restrict__ xpB,
                                                     const u16* __restrict__ wA,
                                                     const u16* __restrict__ wB,
                                                     float* __restrict__ outA,
                                                     float* __restrict__ outB){
  constexpr int K = 27*CIN;
  constexpr int CH = CIN/32;
  constexpr int STEPS = 27*CH;
  constexpr int NT = COUT/32;
  constexpr int NB8 = COUT/32;
  __shared__ __align__(16) u16 As[2][64*40];
  __shared__ __align__(16) u16 Bs[2][COUT*40];
  int tid = threadIdx.x;
  int b0 = blockIdx.x;
  int xcd = b0 & 7, ii = b0 >> 3;
  int bid = (xcd < 6 ? xcd*86 : 516 + (xcd-6)*85) + ii;
  int which = (bid >= 343) ? 1 : 0;
  int t = bid - which*343;
  const u16* xp  = which ? xpB : xpA;
  const u16* wtb = which ? wB : wA;
  float* out = which ? outB : outA;
  int v0 = t*64;
  int sv  = tid>>2;
  int c8u = (tid&3)*8;
  int av = v0 + sv;
  int d = av/784; int rm2 = av - d*784; int hh = rm2/28; int ww = rm2 - hh*28;
  int pbase = (d*30 + hh)*30 + ww;
  int lane = tid&63, wv = tid>>6;
  int lm = lane&15, lq = lane>>4;
  int mbase = (wv>>1)*32;
  int nbase = (wv&1)*(COUT/2);

  float4v acc[2][NT];
  #pragma unroll
  for (int mt=0; mt<2; mt++)
    #pragma unroll
    for (int nt=0; nt<NT; nt++) acc[mt][nt] = (float4v)0.f;

  uint4 a_r;
  uint2 b_r[NB8];
  auto load_s = [&](int s){
    int tp = s/CH, cc = s - tp*CH;
    int td = tp/9, tr = tp - td*9, th = tr/3, tw = tr - th*3;
    int toff = td*900 + th*30 + tw;
    a_r = *(const uint4*)(xp + (size_t)(pbase + toff)*CIN + cc*32 + c8u);
    #pragma unroll
    for (int j=0;j<NB8;j++){
      int bi = tid + j*256;
      int n = bi>>3, c4 = (bi&7)*4;
      b_r[j] = *(const uint2*)(wtb + (size_t)n*K + s*32 + c4);
    }
  };
  auto write_s = [&](int buf){
    *(uint4*)(&As[buf][sv*40 + c8u]) = a_r;
    #pragma unroll
    for (int j=0;j<NB8;j++){
      int bi = tid + j*256;
      int n = bi>>3, c4 = (bi&7)*4;
      *(uint2*)(&Bs[buf][n*40 + c4]) = b_r[j];
    }
  };

  load_s(0);
  write_s(0);
  __syncthreads();
  for (int s = 0; s < STEPS; s++){
    if (s+1 < STEPS) load_s(s+1);
    int buf = s&1;
    short8 aa[2], bb[NT];
    #pragma unroll
    for (int mt=0; mt<2; mt++)
      aa[mt] = *(const short8*)(&As[buf][(mbase + mt*16 + lm)*40 + lq*8]);
    #pragma unroll
    for (int nt=0; nt<NT; nt++)
      bb[nt] = *(const short8*)(&Bs[buf][(nbase + nt*16 + lm)*40 + lq*8]);
    #pragma unroll
    for (int nt=0; nt<NT; nt++)
      #pragma unroll
      for (int mt=0; mt<2; mt++)
        acc[mt][nt] = __builtin_amdgcn_mfma_f32_16x16x32_bf16(aa[mt], bb[nt], acc[mt][nt], 0, 0, 0);
    if (s+1 < STEPS) write_s((s+1)&1);
    __syncthreads();
  }
  #pragma unroll
  for (int mt=0; mt<2; mt++)
    #pragma unroll
    for (int nt=0; nt<NT; nt++)
      #pragma unroll
      for (int r=0; r<4; r++){
        int row = v0 + mbase + mt*16 + lq*4 + r;
        int col = nbase + nt*16 + lm;
        out[(size_t)row*COUT + col] = acc[mt][nt][r];
      }
}

// ---- generic MFMA GEMM; MRG=1 adds a second pointer set for the f-half ----
template<int K, int NF, int GATHER, int ASRC, int EPI, int MRG>
__global__ __launch_bounds__(256) void k_gemm(const float* __restrict__ Af,
                                              const u16* __restrict__ Ab,
                                              const u16* __restrict__ B,
                                              const float* __restrict__ bias,
                                              const float* __restrict__ resid,
                                              float* __restrict__ outf,
                                              u16* __restrict__ out16,
                                              u16* __restrict__ out16b,
                                              float scale,
                                              const u16* __restrict__ B2,
                                              const float* __restrict__ bias2,
                                              const float* __restrict__ resid2,
                                              float* __restrict__ outf2,
                                              u16* __restrict__ out162,
                                              u16* __restrict__ out16b2){
  constexpr int STEPS = K/32;
  constexpr int NB = NF/64;
  __shared__ __align__(16) u16 As[2][64*40];
  __shared__ __align__(16) u16 Bs[2][64*40];
  __shared__ int map[64];
  int tid = threadIdx.x;
  int bid = blockIdx.x;
  int mb = bid / NB, nb = bid - mb*NB;
  int v0 = mb*64, ncol0 = nb*64;
  int half = (MRG && v0 >= LTOT) ? 1 : 0;
  const u16* Bx = half ? B2 : B;
  const float* biasx = half ? bias2 : bias;
  const float* residx = half ? resid2 : resid;
  float* outfx = half ? outf2 : outf;
  u16* out16x = half ? out162 : out16;
  u16* out16bx = half ? out16b2 : out16b;
  int vloc = v0 - half*LTOT;
  if (tid < 64){
    int r = vloc + tid;
    int src;
    if (GATHER == 0){
      src = r;
    } else if (GATHER == 1){
      int w = r/343; int n = r - w*343;
      int nd = w>>4, nh = (w>>2)&3, nw = w&3;
      int i = n/49; int rr = n - i*49; int j = rr/7; int k2 = rr - j*7;
      int dd = nd*7 + i + 3; if (dd >= 28) dd -= 28;
      int hh = nh*7 + j + 3; if (hh >= 28) hh -= 28;
      int ww = nw*7 + k2 + 3; if (ww >= 28) ww -= 28;
      src = (dd*28 + hh)*28 + ww;
    } else {
      int l = r;
      int d = l/784; int rm = l - d*784; int y = rm/28; int x = rm - y*28;
      int dp = d-3; if (dp<0) dp+=28;
      int yp = y-3; if (yp<0) yp+=28;
      int xq = x-3; if (xq<0) xq+=28;
      int nd = dp/7, i = dp - nd*7;
      int nh = yp/7, j = yp - nh*7;
      int nw = xq/7, k2 = xq - nw*7;
      src = ((nd*4+nh)*4+nw)*NTOK + (i*7+j)*7 + k2;
    }
    map[tid] = src + half*LTOT;     // A is contiguous across halves
  }
  __syncthreads();
  int sv = tid>>2, c8 = (tid&3)*8;
  int arow = map[sv];
  int lane = tid&63, wv = tid>>6;
  int lm = lane&15, lq = lane>>4;
  int mbase = (wv>>1)*32, nbase = (wv&1)*32;

  float4v acc[2][2];
  #pragma unroll
  for (int mt=0; mt<2; mt++)
    #pragma unroll
    for (int nt=0; nt<2; nt++) acc[mt][nt] = (float4v)0.f;

  float4 afr0, afr1; uint4 abr; uint4 bvr;
  auto load_s = [&](int s){
    if (ASRC == 0){
      const float* ap = Af + (size_t)arow*K + s*32 + c8;
      afr0 = *(const float4*)ap;
      afr1 = *(const float4*)(ap+4);
    } else {
      abr = *(const uint4*)(Ab + (size_t)arow*K + s*32 + c8);
    }
    bvr = *(const uint4*)(Bx + (size_t)(ncol0 + sv)*K + s*32 + c8);
  };
  auto write_s = [&](int buf){
    if (ASRC == 0){
      uint4 pk;
      pk.x = (u32)f2b(afr0.x) | ((u32)f2b(afr0.y)<<16);
      pk.y = (u32)f2b(afr0.z) | ((u32)f2b(afr0.w)<<16);
      pk.z = (u32)f2b(afr1.x) | ((u32)f2b(afr1.y)<<16);
      pk.w = (u32)f2b(afr1.z) | ((u32)f2b(afr1.w)<<16);
      *(uint4*)(&As[buf][sv*40 + c8]) = pk;
    } else {
      *(uint4*)(&As[buf][sv*40 + c8]) = abr;
    }
    *(uint4*)(&Bs[buf][sv*40 + c8]) = bvr;
  };

  load_s(0);
  write_s(0);
  __syncthreads();
  for (int s = 0; s < STEPS; s++){
    if (s+1 < STEPS) load_s(s+1);
    int buf = s&1;
    short8 aa[2], bb[2];
    #pragma unroll
    for (int mt=0; mt<2; mt++)
      aa[mt] = *(const short8*)(&As[buf][(mbase + mt*16 + lm)*40 + lq*8]);
    #pragma unroll
    for (int nt=0; nt<2; nt++)
      bb[nt] = *(const short8*)(&Bs[buf][(nbase + nt*16 + lm)*40 + lq*8]);
    #pragma unroll
    for (int nt=0; nt<2; nt++)
      #pragma unroll
      for (int mt=0; mt<2; mt++)
        acc[mt][nt] = __builtin_amdgcn_mfma_f32_16x16x32_bf16(aa[mt], bb[nt], acc[mt][nt], 0, 0, 0);
    if (s+1 < STEPS) write_s((s+1)&1);
    __syncthreads();
  }
  // epilogue
  float bv[2];
  #pragma unroll
  for (int nt=0; nt<2; nt++) bv[nt] = biasx ? biasx[ncol0 + nbase + nt*16 + lm] : 0.f;
  #pragma unroll
  for (int mt=0; mt<2; mt++){
    #pragma unroll
    for (int r=0; r<4; r++){
      int row = v0 + mbase + mt*16 + lq*4 + r;
      int rowl = row - half*LTOT;
      if (EPI == 0 || EPI == 3){
        int w = rowl/343; int tok = rowl - w*343;
        #pragma unroll
        for (int nt=0; nt<2; nt++){
          int col = ncol0 + nbase + nt*16 + lm;
          float val = (acc[mt][nt][r] + bv[nt]) * scale;
          if (EPI == 0){
            int h = col>>5, c = col&31;
            out16x[((size_t)(w*6 + h)*343 + tok)*32 + c] = f2b(val);
          } else {
            u16* dst = (col < 192) ? out16x : out16bx;
            int cc = (col < 192) ? col : col - 192;
            int h = cc>>5, c = cc&31;
            dst[((size_t)(w*6 + h)*343 + tok)*32 + c] = f2b(val);
          }
        }
      } else if (EPI == 1){
        #pragma unroll
        for (int nt=0; nt<2; nt++){
          int col = ncol0 + nbase + nt*16 + lm;
          size_t o = (size_t)rowl*NF + col;
          outfx[o] = acc[mt][nt][r] + bv[nt] + residx[o];
        }
      } else {
        #pragma unroll
        for (int nt=0; nt<2; nt++){
          int col = ncol0 + nbase + nt*16 + lm;
          float v = acc[mt][nt][r] + bv[nt];
          float gl = 0.5f*v*(1.f + erff(v*0.70710678118f));
          out16[(size_t)row*NF + col] = f2b(gl);   // fc1: single global hs
        }
      }
    }
  }
}

// ---- BN stats, merged m+f: grid 128, x = contiguous [2L][C] ---------------
__global__ __launch_bounds__(192) void k_bnsum(const float* __restrict__ x, int C,
                                               float* __restrict__ psum){
  int bid = blockIdx.x, t = threadIdx.x;
  int rpi = 192/C;
  int c  = (C==192) ? t : (t % 96);
  int ro = (C==192) ? 0 : (t / 96);
  float s=0.f, s2=0.f;
  int base = bid*343;
  for (int r = ro; r < 343; r += rpi){
    float v = x[(size_t)(base+r)*C + c];
    s += v; s2 += v*v;
  }
  psum[(size_t)bid*384 + t]       = s;
  psum[(size_t)bid*384 + 192 + t] = s2;
}
__global__ void k_bnfin2(const float* __restrict__ psum, int C,
                         const float* __restrict__ g0, const float* __restrict__ bb0,
                         const float* __restrict__ g1, const float* __restrict__ bb1,
                         float* a0, float* b0o, float* a1, float* b1o){
  int h = blockIdx.x;
  int c = threadIdx.x;
  if (c >= C) return;
  const float* g  = h ? g1 : g0;
  const float* bb = h ? bb1 : bb0;
  float* ao = h ? a1 : a0;
  float* bo = h ? b1o : b0o;
  const float* ps = psum + (size_t)h*64*384;
  int slots = 192/C;
  float s=0.f, s2=0.f;
  for (int b=0; b<64; b++)
    for (int k=0; k<slots; k++){
      s  += ps[(size_t)b*384 + k*C + c];
      s2 += ps[(size_t)b*384 + 192 + k*C + c];
    }
  float mu = s/(float)LTOT;
  float var = s2/(float)LTOT - mu*mu;
  float rstd = rsqrtf(var + 1e-5f);
  float aa = rstd * g[c];
  ao[c] = aa;
  bo[c] = bb[c] - mu*aa;
}

// ------------- conv3 1x1x1 merged m+f: grid 2L -----------------------------
__global__ __launch_bounds__(96) void k_flow(const float* __restrict__ t2,
                                             const float* __restrict__ a2b,
                                             const float* __restrict__ w3m,
                                             const float* __restrict__ w3f,
                                             float* __restrict__ flow){
  __shared__ float xr[96];
  int l = blockIdx.x; int t = threadIdx.x;
  int half = l >= LTOT; int ll = l - half*LTOT;
  const float* a2 = a2b + half*192; const float* b2 = a2 + 96;
  const float* w3 = half ? w3f : w3m;
  float xv = t2[(size_t)l*96 + t];
  xr[t] = fmaxf(xv*a2[t] + b2[t], 0.f);
  __syncthreads();
  if (t < 18){
    float acc = 0.f;
    for (int c=0;c<96;c++) acc += xr[c]*w3[t*96 + c];
    flow[((size_t)half*18 + t)*LTOT + ll] = acc;
  }
}

// ------------- trilinear warp merged m+f: grid 2L --------------------------
__global__ __launch_bounds__(192) void k_warp(const float* __restrict__ src,
                                              const float* __restrict__ flow, float* __restrict__ dst){
  int l = blockIdx.x; int tid = threadIdx.x; int hh = tid>>5;
  int half = l >= LTOT; int ll = l - half*LTOT;
  const float* s_ = src + (size_t)half*LTOT*192;
  int d = ll/784; int rm = ll - d*784; int y = rm/28; int x = rm - y*28;
  float fd = flow[((size_t)half*18 + hh*3+0)*LTOT + ll];
  float fy = flow[((size_t)half*18 + hh*3+1)*LTOT + ll];
  float fx = flow[((size_t)half*18 + hh*3+2)*LTOT + ll];
  float cd = fminf(fmaxf((float)d + fd, 0.f), 27.f);
  float cy = fminf(fmaxf((float)y + fy, 0.f), 27.f);
  float cx = fminf(fmaxf((float)x + fx, 0.f), 27.f);
  int d0 = (int)floorf(cd); int d1 = min(d0+1, 27);
  int y0 = (int)floorf(cy); int y1 = min(y0+1, 27);
  int x0 = (int)floorf(cx); int x1 = min(x0+1, 27);
  float wd = cd - (float)d0, wy = cy - (float)y0, wx = cx - (float)x0;
  #define SMP(di,yi,xi) s_[(size_t)(((di)*28+(yi))*28+(xi))*192 + tid]
  float v000 = SMP(d0,y0,x0), v001 = SMP(d0,y0,x1), v010 = SMP(d0,y1,x0), v011 = SMP(d0,y1,x1);
  float v100 = SMP(d1,y0,x0), v101 = SMP(d1,y0,x1), v110 = SMP(d1,y1,x0), v111 = SMP(d1,y1,x1);
  #undef SMP
  float o = v000*(1-wd)*(1-wy)*(1-wx) + v001*(1-wd)*(1-wy)*wx
          + v010*(1-wd)*wy*(1-wx)     + v011*(1-wd)*wy*wx
          + v100*wd*(1-wy)*(1-wx)     + v101*wd*(1-wy)*wx
          + v110*wd*wy*(1-wx)         + v111*wd*wy*wx;
  dst[(size_t)l*192 + tid] = o;
}

// ------------ MFMA attention merged (both directions): grid 4608 -----------
__global__ __launch_bounds__(256) void k_attmfma(const u16* __restrict__ Q1,
                                                 const u16* __restrict__ K1,
                                                 const u16* __restrict__ V1,
                                                 const u16* __restrict__ Q2,
                                                 const u16* __restrict__ K2,
                                                 const u16* __restrict__ V2,
                                                 const float* __restrict__ bm,
                                                 float* __restrict__ ctx1,
                                                 float* __restrict__ ctx2){
  __shared__ __align__(16) u16 Kl[352*40];      // [key][40]
  __shared__ __align__(16) u16 Vt[32*360];      // [dim][360]
  __shared__ __align__(16) u16 Pl[4][2][16*40]; // per-wave, dbuf
  int bid0 = blockIdx.x;
  int halfsel = bid0 >= 2304;
  int bid = bid0 - halfsel*2304;
  const u16* Q = halfsel ? Q2 : Q1;
  const u16* K = halfsel ? K2 : K1;
  const u16* V = halfsel ? V2 : V1;
  float* ctx = halfsel ? ctx2 : ctx1;
  int wh = bid/6, qg = bid - (bid/6)*6;
  int w = wh/6, h = wh - w*6;
  int tid = threadIdx.x;
  int nd = w>>4, nh = (w>>2)&3, nw = w&3;
  int type = ((nd==3)?4:0) | ((nh==3)?2:0) | ((nw==3)?1:0);
  const u16* kb = K + (size_t)wh*10976;
  const u16* vbp = V + (size_t)wh*10976;
  for (int idx=tid; idx<343*4; idx+=256){
    int row = idx>>2, c8 = (idx&3)*8;
    uint4 val = *(const uint4*)(kb + row*32 + c8);
    *(uint4*)(&Kl[row*40 + c8]) = val;
  }
  for (int idx=tid; idx<9*40; idx+=256) Kl[343*40 + idx] = 0;
  for (int idx=tid; idx<343*4; idx+=256){
    int row = idx>>2, c8 = (idx&3)*8;
    uint4 val = *(const uint4*)(vbp + row*32 + c8);
    const u16* pv = (const u16*)&val;
    #pragma unroll
    for (int j=0;j<8;j++) Vt[(c8+j)*360 + row] = pv[j];
  }
  for (int idx=tid; idx<32*17; idx+=256){
    int dd = idx/17, cc = 343 + idx - (idx/17)*17;
    Vt[dd*360 + cc] = 0;
  }
  __syncthreads();
  int lane = tid&63, wv = tid>>6;
  int lm = lane&15, lq = lane>>4;
  const float* bmh = bm + (size_t)(type*6 + h)*123904;
  int qt = qg*4 + wv;
  if (qt < 22){
    int q0 = qt*16;
    short8 bq = *(const short8*)(Q + (size_t)wh*10976 + (q0+lm)*32 + lq*8);
    float4v sc[22];
    #pragma unroll
    for (int kt=0; kt<22; kt++){
      short8 ak = *(const short8*)(&Kl[(kt*16+lm)*40 + lq*8]);
      sc[kt] = __builtin_amdgcn_mfma_f32_16x16x32_bf16(ak, bq, (float4v)0.f, 0, 0, 0);
    }
    const float* bcol = bmh + q0 + lm;
    float mx = -3.0e38f;
    #pragma unroll
    for (int kt=0; kt<22; kt++){
      #pragma unroll
      for (int r=0; r<4; r++){
        int key = kt*16 + lq*4 + r;
        float s = sc[kt][r] + bcol[(size_t)key*352];
        sc[kt][r] = s;
        mx = fmaxf(mx, s);
      }
    }
    mx = fmaxf(mx, __shfl_xor(mx, 16));
    mx = fmaxf(mx, __shfl_xor(mx, 32));
    float sm = 0.f;
    #pragma unroll
    for (int kt=0; kt<22; kt++){
      #pragma unroll
      for (int r=0; r<4; r++){
        float p = __expf(sc[kt][r] - mx);
        sc[kt][r] = p;
        sm += p;
      }
    }
    sm += __shfl_xor(sm, 16);
    sm += __shfl_xor(sm, 32);
    float inv = 1.f/sm;
    float4v o0 = (float4v)0.f, o1 = (float4v)0.f;
    #pragma unroll
    for (int s=0; s<11; s++){
      u16* pw = &Pl[wv][s&1][0];
      #pragma unroll
      for (int hf=0; hf<2; hf++){
        int kt = 2*s + hf;
        uint2 pv2;
        pv2.x = (u32)f2b(sc[kt][0]) | ((u32)f2b(sc[kt][1])<<16);
        pv2.y = (u32)f2b(sc[kt][2]) | ((u32)f2b(sc[kt][3])<<16);
        *(uint2*)(&pw[lm*40 + hf*16 + lq*4]) = pv2;
      }
      short8 bp = *(const short8*)(&pw[lm*40 + lq*8]);
      short8 a0 = *(const short8*)(&Vt[lm*360 + s*32 + lq*8]);
      short8 a1 = *(const short8*)(&Vt[(16+lm)*360 + s*32 + lq*8]);
      o0 = __builtin_amdgcn_mfma_f32_16x16x32_bf16(a0, bp, o0, 0, 0, 0);
      o1 = __builtin_amdgcn_mfma_f32_16x16x32_bf16(a1, bp, o1, 0, 0, 0);
    }
    int query = q0 + lm;
    if (query < 343){
      float* ob = ctx + ((size_t)w*NTOK + query)*192 + h*32;
      float4 t0, t1v;
      t0.x = o0[0]*inv; t0.y = o0[1]*inv; t0.z = o0[2]*inv; t0.w = o0[3]*inv;
      t1v.x = o1[0]*inv; t1v.y = o1[1]*inv; t1v.z = o1[2]*inv; t1v.w = o1[3]*inv;
      *(float4*)(ob + lq*4) = t0;
      *(float4*)(ob + 16 + lq*4) = t1v;
    }
  }
}

// ===========================================================================
extern "C" void kernel_launch(void* const* d_in, const int* in_sizes, int n_in,
                              void* d_out, int out_size, void* d_ws, size_t ws_size,
                              hipStream_t stream){
  const float* mov     = (const float*)d_in[0];
  const float* fix     = (const float*)d_in[1];
  const float* n1g     = (const float*)d_in[2];
  const float* n1b     = (const float*)d_in[3];
  const float* offm_w1 = (const float*)d_in[4];
  const float* offm_g1 = (const float*)d_in[5];
  const float* offm_b1 = (const float*)d_in[6];
  const float* offm_w2 = (const float*)d_in[7];
  const float* offm_g2 = (const float*)d_in[8];
  const float* offm_b2 = (const float*)d_in[9];
  const float* offm_w3 = (const float*)d_in[10];
  const float* offf_w1 = (const float*)d_in[11];
  const float* offf_g1 = (const float*)d_in[12];
  const float* offf_b1 = (const float*)d_in[13];
  const float* offf_w2 = (const float*)d_in[14];
  const float* offf_g2 = (const float*)d_in[15];
  const float* offf_b2 = (const float*)d_in[16];
  const float* offf_w3 = (const float*)d_in[17];
  const float* mq_w    = (const float*)d_in[18];
  const float* mkv_w   = (const float*)d_in[19];
  const float* fq_w    = (const float*)d_in[20];
  const float* fkv_w   = (const float*)d_in[21];
  const float* mproj_w = (const float*)d_in[22];
  const float* fproj_w = (const float*)d_in[23];
  const float* mq_b    = (const float*)d_in[24];
  const float* mkv_b   = (const float*)d_in[25];
  const float* fq_b    = (const float*)d_in[26];
  const float* fkv_b   = (const float*)d_in[27];
  const float* mproj_b = (const float*)d_in[28];
  const float* fproj_b = (const float*)d_in[29];
  const float* rpbt    = (const float*)d_in[30];
  const float* n2g     = (const float*)d_in[31];
  const float* n2b     = (const float*)d_in[32];
  const float* fc1_w   = (const float*)d_in[33];
  const float* fc1_b   = (const float*)d_in[34];
  const float* fc2_w   = (const float*)d_in[35];
  const float* fc2_b   = (const float*)d_in[36];
  float* outp = (float*)d_out;

  float* W = (float*)d_ws;
  const size_t L192 = (size_t)LTOT*192;   // floats per region (16.86 MB)
  // conv-phase layout:
  float* m_   = W;                         // region 0
  float* f_   = W + 1*L192;                // region 1
  float* t1   = W + 2*L192;                // regions 2,3 ([2L][192])
  u16* xp     = (u16*)(W + 4*L192);        // 27000*384 u16
  u16* xp2    = xp + (size_t)27000*384;    // 54000*192 u16, contiguous m|f
  float* sb   = W + 6*L192 + 3000000;      // stats block
  float* a1m = sb,       *b1m = sb+192;
  float* a1f = sb+384,   *b1f = sb+576;
  float* a2m = sb+768,   *b2m = sb+864;
  float* a2f = sb+960,   *b2f = sb+1056;
  float* psum = sb + 1536;                 // 128*384 floats
  float* flowm = W + 6*L192 + 3100000;     // [36][LTOT]
  float* t2   = W + 7*L192;                // [2L][96]
  u16* wt1m = (u16*)(W + 8*L192);          // conv weights, region 8
  u16* wt1f = wt1m + 192*10368;
  u16* wt2m = wt1f + 192*10368;
  u16* wt2f = wt2m + 96*5184;
  // post-conv reuse:
  float* dmov = W + 4*L192;                // region 4
  float* dfix = W + 5*L192;                // region 5
  float* ctxm = dmov; float* ctxf = dfix;
  float* mout = m_;   float* fout = f_;
  u16* QMb = (u16*)(W + 6*L192);
  u16* QFb = (u16*)(W + 7*L192);
  u16* Kmb = (u16*)(W + 2*L192);
  u16* Vmb = (u16*)(W + 3*L192);
  u16* Kfb = (u16*)(W + 8*L192);
  u16* Vfb = (u16*)(W + 9*L192);
  float* bm = W;
  u16* wq_m  = (u16*)(W + 9*L192) + 4214784;
  u16* wq_f  = wq_m  + 36864;
  u16* wkv_m = wq_f  + 36864;
  u16* wkv_f = wkv_m + 73728;
  u16* wpj_m = wkv_f + 73728;
  u16* wpj_f = wpj_m + 36864;
  u16* wfc1  = wpj_f + 36864;
  u16* wfc2  = wfc1  + 147456;
  u16* hs16  = (u16*)(W + 2*L192);         // [2L][768] regions 2-5
  float* lnbuf = W + 6*L192;               // [2L][192] regions 6,7

  // weight prep (3 launches)
  k_prepw1b<<<(2*192*10368+255)/256, 256, 0, stream>>>(offm_w1, offf_w1, wt1m, wt1f);
  k_prepw2b<<<(2*96*5184+255)/256, 256, 0, stream>>>(offm_w2, offf_w2, wt2m, wt2f);
  k_prepwb8<<<2304, 256, 0, stream>>>(mq_w, fq_w, mkv_w, fkv_w, mproj_w, fproj_w, fc1_w, fc2_w,
                                      wq_m, wq_f, wkv_m, wkv_f, wpj_m, wpj_f, wfc1, wfc2);
  // layernorm1
  k_ln<<<2*LTOT, 64, 0, stream>>>(mov, fix, n1g, n1b, m_, f_);
  // padded bf16 volume [m|f]
  k_pad1<<<27000, 192, 0, stream>>>(m_, f_, xp);
  // conv1 (r7 winner: 4-wave 64x48, tri-buffered, counted vmcnt)
  k_conv1dma<<<686, 256, 0, stream>>>(xp, wt1m, wt1f, t1, t1 + 2*L192);
  k_bnsum<<<128, 192, 0, stream>>>(t1, 192, psum);
  k_bnfin2<<<2, 192, 0, stream>>>(psum, 192, offm_g1, offm_b1, offf_g1, offf_b1, a1m, b1m, a1f, b1f);
  k_pad2<<<54000, 192, 0, stream>>>(t1, sb, xp2);
  // conv2 (m+f halves of contiguous xp2)
  k_convmfma<192,96><<<686, 256, 0, stream>>>(xp2, xp2 + (size_t)27000*192, wt2m, wt2f,
                                              t2, t2 + (size_t)LTOT*96);
  k_bnsum<<<128, 192, 0, stream>>>(t2, 96, psum);
  k_bnfin2<<<2, 96, 0, stream>>>(psum, 96, offm_g2, offm_b2, offf_g2, offf_b2, a2m, b2m, a2f, b2f);
  k_flow<<<2*LTOT, 96, 0, stream>>>(t2, sb+768, offm_w3, offf_w3, flowm);
  // deformable warp (merged)
  k_warp<<<2*LTOT, 192, 0, stream>>>(m_, flowm, dmov);
  // windowed projections (merged m+f)
  const float scale = 0.17677669529663687f; // 32^-0.5
  k_gemm<192,192,1,0,0,1><<<2*343*3, 256, 0, stream>>>(dmov, nullptr, wq_m, mq_b, nullptr, nullptr, QMb, nullptr, scale,
                                                       wq_f, fq_b, nullptr, nullptr, QFb, nullptr);
  k_gemm<192,384,1,0,3,1><<<2*343*6, 256, 0, stream>>>(m_, nullptr, wkv_m, mkv_b, nullptr, nullptr, Kmb, Vmb, 1.f,
                                                       wkv_f, fkv_b, nullptr, nullptr, Kfb, Vfb);
  // bias matrix (m_/f_ now dead)
  k_prepbias<<<(48*123904+255)/256, 256, 0, stream>>>(rpbt, bm);
  // attention merged: mo = attend(dfQ, mK, mV); fo = attend(dmQ, fK, fV)
  k_attmfma<<<4608, 256, 0, stream>>>(QFb, Kmb, Vmb, QMb, Kfb, Vfb, bm, ctxm, ctxf);
  // proj + residual + window-reverse (merged)
  k_gemm<192,192,2,0,1,1><<<2*343*3, 256, 0, stream>>>(ctxm, nullptr, wpj_m, mproj_b, mov, mout, nullptr, nullptr, 1.f,
                                                       wpj_f, fproj_b, fix, fout, nullptr, nullptr);
  // MLP both halves (contiguous rows)
  k_ln1<<<2*LTOT, 64, 0, stream>>>(mout, n2g, n2b, lnbuf);
  k_gemm<192,768,0,0,2,0><<<2*343*12, 256, 0, stream>>>(lnbuf, nullptr, wfc1, fc1_b, nullptr, nullptr, hs16, nullptr, 1.f,
                                                        nullptr, nullptr, nullptr, nullptr, nullptr, nullptr);
  k_gemm<768,192,0,1,1,0><<<2*343*3, 256, 0, stream>>>(nullptr, hs16, wfc2, fc2_b, mout, outp, nullptr, nullptr, 1.f,
                                                       nullptr, nullptr, nullptr, nullptr, nullptr, nullptr);
}

// Round 10
// 1192.511 us; speedup vs baseline: 1.1490x; 1.0183x over previous
//
#include <hip/hip_runtime.h>

#define LTOT 21952      // 28^3
#define NTOK 343        // 7^3

typedef unsigned short u16;
typedef unsigned int   u32;
typedef __attribute__((ext_vector_type(8))) short short8;
typedef __attribute__((ext_vector_type(4))) float float4v;

__device__ __forceinline__ u16 f2b(float f){
  u32 x = __float_as_uint(f);
  u32 r = (x + 0x7fffu + ((x>>16)&1u)) >> 16;
  return (u16)r;
}

// 16B global -> LDS direct DMA (HW dest = wave-uniform base + lane*16)
__device__ __forceinline__ void dma16(const u16* g, u16* l){
  __builtin_amdgcn_global_load_lds((const __attribute__((address_space(1))) u32*)g,
                                   (__attribute__((address_space(3))) u32*)l,
                                   16, 0, 0);
}

// ---------------- LayerNorm (norm1) : f32 in -> f32 out --------------------
__global__ __launch_bounds__(64) void k_ln(const float* __restrict__ mov, const float* __restrict__ fix,
                                           const float* __restrict__ g, const float* __restrict__ b,
                                           float* __restrict__ om, float* __restrict__ of){
  int row = blockIdx.x;
  const float* src; float* dst;
  if (row < LTOT){ src = mov + (size_t)row*192; dst = om + (size_t)row*192; }
  else          { src = fix + (size_t)(row-LTOT)*192; dst = of + (size_t)(row-LTOT)*192; }
  int t = threadIdx.x;
  float x0 = src[t], x1 = src[t+64], x2 = src[t+128];
  float s = x0+x1+x2, s2 = x0*x0 + x1*x1 + x2*x2;
  for (int o=32;o;o>>=1){ s += __shfl_xor(s,o); s2 += __shfl_xor(s2,o); }
  float mu = s*(1.f/192.f);
  float var = s2*(1.f/192.f) - mu*mu;
  float rs = rsqrtf(var + 1e-5f);
  dst[t]     = (x0-mu)*rs*g[t]     + b[t];
  dst[t+64]  = (x1-mu)*rs*g[t+64]  + b[t+64];
  dst[t+128] = (x2-mu)*rs*g[t+128] + b[t+128];
}

// ---------------- LayerNorm (norm2), single buffer, rows may span 2L -------
__global__ __launch_bounds__(64) void k_ln1(const float* __restrict__ x,
                                            const float* __restrict__ g, const float* __restrict__ b,
                                            float* __restrict__ y){
  int row = blockIdx.x;
  const float* src = x + (size_t)row*192;
  float* dst = y + (size_t)row*192;
  int t = threadIdx.x;
  float x0 = src[t], x1 = src[t+64], x2 = src[t+128];
  float s = x0+x1+x2, s2 = x0*x0 + x1*x1 + x2*x2;
  for (int o=32;o;o>>=1){ s += __shfl_xor(s,o); s2 += __shfl_xor(s2,o); }
  float mu = s*(1.f/192.f);
  float var = s2*(1.f/192.f) - mu*mu;
  float rs = rsqrtf(var + 1e-5f);
  dst[t]     = (x0-mu)*rs*g[t]     + b[t];
  dst[t+64]  = (x1-mu)*rs*g[t+64]  + b[t+64];
  dst[t+128] = (x2-mu)*rs*g[t+128] + b[t+128];
}

// ------ conv1 weight prep (m+f merged): f32 -> w1t[s][wv][192][8] bf16 -----
__global__ void k_prepw1b(const float* __restrict__ sm, const float* __restrict__ sf,
                          u16* __restrict__ dm, u16* __restrict__ df){
  int idx = blockIdx.x*256 + threadIdx.x;
  if (idx >= 2*192*10368) return;
  int half = idx >= 192*10368;
  int i = idx - half*192*10368;
  const float* src = half ? sf : sm;
  u16* dst = half ? df : dm;
  int swap = half ? 192 : 0;
  int c8 = i & 7;
  int t2 = i >> 3;
  int n  = t2 % 192;
  int sw = t2 / 192;
  int k  = (sw>>2)*32 + (sw&3)*8 + c8;
  int t  = k / 384; int c = k - t*384;
  int cs = c + swap; if (cs >= 384) cs -= 384;
  dst[i] = f2b(src[((size_t)n*384 + cs)*27 + t]);
}
// ------ conv2 weight prep (m+f merged): (96,192,27) -> [n][t*192+c] --------
__global__ void k_prepw2b(const float* __restrict__ sm, const float* __restrict__ sf,
                          u16* __restrict__ dm, u16* __restrict__ df){
  int idx = blockIdx.x*256 + threadIdx.x;
  if (idx >= 2*96*5184) return;
  int half = idx >= 96*5184;
  int i = idx - half*96*5184;
  const float* src = half ? sf : sm;
  u16* dst = half ? df : dm;
  int n = i / 5184; int k = i - n*5184;
  int t = k / 192; int c = k - t*192;
  dst[i] = f2b(src[((size_t)n*192 + c)*27 + t]);
}
// ------ all 8 GEMM weight copies in one launch -----------------------------
__global__ void k_prepwb8(const float* s0,const float* s1,const float* s2,const float* s3,
                          const float* s4,const float* s5,const float* s6,const float* s7,
                          u16* d0,u16* d1,u16* d2,u16* d3,u16* d4,u16* d5,u16* d6,u16* d7){
  int idx = blockIdx.x*256 + threadIdx.x;
  if      (idx < 36864)  d0[idx]        = f2b(s0[idx]);
  else if (idx < 73728)  d1[idx-36864]  = f2b(s1[idx-36864]);
  else if (idx < 147456) d2[idx-73728]  = f2b(s2[idx-73728]);
  else if (idx < 221184) d3[idx-147456] = f2b(s3[idx-147456]);
  else if (idx < 258048) d4[idx-221184] = f2b(s4[idx-221184]);
  else if (idx < 294912) d5[idx-258048] = f2b(s5[idx-258048]);
  else if (idx < 442368) d6[idx-294912] = f2b(s6[idx-294912]);
  else if (idx < 589824) d7[idx-442368] = f2b(s7[idx-442368]);
}

// ------ bias matrix prep: [type 8][head 6][key 352][query 352] f32 ---------
__global__ void k_prepbias(const float* __restrict__ rpt, float* __restrict__ bm){
  int idx = blockIdx.x*256 + threadIdx.x;
  if (idx >= 48*123904) return;
  int th = idx / 123904; int r = idx - th*123904;
  int key = r / 352; int q = r - key*352;
  int type = th / 6; int h = th - type*6;
  float v;
  if (key >= 343 || q >= 343){
    v = -30000.f;
  } else {
    int ki = key/49, kj = (key/7)%7, kk = key%7;
    int qi = q/49,   qj = (q/7)%7,   qk = q%7;
    int ridx = ((qi-ki+6)*13 + (qj-kj+6))*13 + (qk-kk+6);
    float rv = rpt[ridx*6 + h];
    int bd = (type>>2)&1, bh = (type>>1)&1, bw = type&1;
    int lq_ = (bd?((qi<4)?1:2):0)*9 + (bh?((qj<4)?1:2):0)*3 + (bw?((qk<4)?1:2):0);
    int lk_ = (bd?((ki<4)?1:2):0)*9 + (bh?((kj<4)?1:2):0)*3 + (bw?((kk<4)?1:2):0);
    v = rv + ((lq_==lk_) ? 0.f : -100.f);
  }
  bm[idx] = v;
}

// ------ padded volume builders (30^3, zero borders), bf16 ------------------
__global__ __launch_bounds__(192) void k_pad1(const float* __restrict__ m_, const float* __restrict__ f_,
                                              u16* __restrict__ xp){
  int p = blockIdx.x; int t = threadIdx.x;
  int pd = p/900; int r = p - pd*900; int ph = r/30; int pw = r - ph*30;
  int d = pd-1, h = ph-1, w = pw-1;
  u16 vm = 0, vf = 0;
  if ((unsigned)d < 28u && (unsigned)h < 28u && (unsigned)w < 28u){
    size_t l = (size_t)((d*28+h)*28+w)*192 + t;
    vm = f2b(m_[l]); vf = f2b(f_[l]);
  }
  xp[(size_t)p*384 + t] = vm;
  xp[(size_t)p*384 + 192 + t] = vf;
}
// pad2 merged m+f: grid 54000; xp2 contiguous [54000][192]
__global__ __launch_bounds__(192) void k_pad2(const float* __restrict__ t1,
                                              const float* __restrict__ sb_,
                                              u16* __restrict__ xp2){
  int p = blockIdx.x; int t = threadIdx.x;
  int half = (p >= 27000); int pl = p - half*27000;
  const float* a1 = sb_ + half*384; const float* b1 = a1 + 192;
  int pd = pl/900; int r = pl - pd*900; int ph = r/30; int pw = r - ph*30;
  int d = pd-1, h = ph-1, w = pw-1;
  u16 v = 0;
  if ((unsigned)d < 28u && (unsigned)h < 28u && (unsigned)w < 28u){
    float xv = t1[((size_t)half*LTOT + (d*28+h)*28+w)*192 + t];
    v = f2b(fmaxf(xv*a1[t] + b1[t], 0.f));
  }
  xp2[(size_t)p*192 + t] = v;
}

// ------ conv1: tri-buffered DMA-B / reg-A, counted vmcnt + raw barrier -----
// grid 686 (343 m-tiles x 2 weight halves), 256 thr, 4 waves of 64x48.
// Prefetch depth 2: at each barrier only the newest 3 B-DMAs stay in flight.
// Rule-18 fences: sched_barrier(0) after each inline-asm waitcnt.
// [r7 WINNER config: 312us, 3 blocks/CU resident, MfmaUtil 24%]
__global__ __launch_bounds__(256, 3) void k_conv1dma(const u16* __restrict__ xp,
                                                     const u16* __restrict__ wmT,
                                                     const u16* __restrict__ wfT,
                                                     float* __restrict__ outm,
                                                     float* __restrict__ outf){
  __shared__ __align__(16) u16 As[3][64*40];    // 15.4 KB
  __shared__ __align__(16) u16 Bs[3][4*1544];   // 37.1 KB
  int tid = threadIdx.x;
  // bijective XCD swizzle over nwg=686: q=85, r=6
  int b0 = blockIdx.x;
  int xcd = b0 & 7, ii = b0 >> 3;
  int bid = (xcd < 6 ? xcd*86 : 516 + (xcd-6)*85) + ii;
  int half = (bid >= 343) ? 1 : 0;
  int t = bid - half*343;
  const u16* wtb = half ? wfT : wmT;
  float* out = half ? outf : outm;
  int v0 = t*64;
  int sv  = tid>>2;                 // A staging row
  int c8u = (tid&3)*8;
  int av = v0 + sv;
  int d = av/784; int rm2 = av - d*784; int hh = rm2/28; int ww = rm2 - hh*28;
  int pbase = (d*30 + hh)*30 + ww;
  int lane = tid&63, wv = tid>>6;
  int lm = lane&15, lq = lane>>4;
  int nbase = wv*48;

  float4v acc[4][3];
  #pragma unroll
  for (int mt=0; mt<4; mt++)
    #pragma unroll
    for (int nt=0; nt<3; nt++) acc[mt][nt] = (float4v)0.f;

  uint4 a_r;
  auto loadA = [&](int s){
    int tp = s/12, cc = s - tp*12;          // CH = 384/32 = 12
    int td = tp/9, tr = tp - td*9, th = tr/3, tw = tr - th*3;
    int toff = td*900 + th*30 + tw;
    a_r = *(const uint4*)(xp + (size_t)(pbase + toff)*384 + cc*32 + c8u);
  };
  auto dmaB = [&](int buf, int s){
    const u16* bsrc = wtb + ((size_t)(s*4 + wv)*192)*8 + (size_t)lane*8;
    #pragma unroll
    for (int j=0;j<3;j++)
      dma16(bsrc + j*512, &Bs[buf][wv*1544 + j*512]);
  };
  auto writeA = [&](int buf){
    *(uint4*)(&As[buf][sv*40 + c8u]) = a_r;
  };

  // prologue: fill buffers 0 and 1
  loadA(0); dmaB(0, 0); writeA(0);
  loadA(1); dmaB(1, 1); writeA(1);
  asm volatile("s_waitcnt vmcnt(3) lgkmcnt(0)" ::: "memory");
  __builtin_amdgcn_sched_barrier(0);
  __builtin_amdgcn_s_barrier();
  int cur = 0;
  for (int s = 0; s < 324; s++){
    int pf = cur + 2; if (pf >= 3) pf -= 3;
    if (s < 322){ loadA(s+2); dmaB(pf, s+2); }
    short8 aa[4], bb[3];
    #pragma unroll
    for (int mt=0; mt<4; mt++)
      aa[mt] = *(const short8*)(&As[cur][(mt*16 + lm)*40 + lq*8]);
    #pragma unroll
    for (int nt=0; nt<3; nt++)
      bb[nt] = *(const short8*)(&Bs[cur][lq*1544 + (nbase + nt*16 + lm)*8]);
    #pragma unroll
    for (int nt=0; nt<3; nt++)
      #pragma unroll
      for (int mt=0; mt<4; mt++)
        acc[mt][nt] = __builtin_amdgcn_mfma_f32_16x16x32_bf16(aa[mt], bb[nt], acc[mt][nt], 0, 0, 0);
    if (s < 322){
      writeA(pf);
      asm volatile("s_waitcnt vmcnt(3) lgkmcnt(0)" ::: "memory");
      __builtin_amdgcn_sched_barrier(0);
    } else {
      asm volatile("s_waitcnt vmcnt(0) lgkmcnt(0)" ::: "memory");
      __builtin_amdgcn_sched_barrier(0);
    }
    __builtin_amdgcn_s_barrier();
    cur++; if (cur >= 3) cur = 0;
  }
  #pragma unroll
  for (int mt=0; mt<4; mt++)
    #pragma unroll
    for (int nt=0; nt<3; nt++)
      #pragma unroll
      for (int r=0; r<4; r++){
        int row = v0 + mt*16 + lq*4 + r;
        int col = nbase + nt*16 + lm;
        out[(size_t)row*192 + col] = acc[mt][nt][r];
      }
}

// ------ conv2 implicit-GEMM MFMA (verified round-2 structure) --------------
template<int CIN, int COUT>
__global__ __launch_bounds__(256, 4) void k_convmfma(const u16* __restrict__ xpA,
                                                     const u16* __restrict__ xpB,
                                                     const u16* __restrict__ wA,
                                                     const u16* __restrict__ wB,
                                                     float* __restrict__ outA,
                                                     float* __restrict__ outB){
  constexpr int K = 27*CIN;
  constexpr int CH = CIN/32;
  constexpr int STEPS = 27*CH;
  constexpr int NT = COUT/32;
  constexpr int NB8 = COUT/32;
  __shared__ __align__(16) u16 As[2][64*40];
  __shared__ __align__(16) u16 Bs[2][COUT*40];
  int tid = threadIdx.x;
  int b0 = blockIdx.x;
  int xcd = b0 & 7, ii = b0 >> 3;
  int bid = (xcd < 6 ? xcd*86 : 516 + (xcd-6)*85) + ii;
  int which = (bid >= 343) ? 1 : 0;
  int t = bid - which*343;
  const u16* xp  = which ? xpB : xpA;
  const u16* wtb = which ? wB : wA;
  float* out = which ? outB : outA;
  int v0 = t*64;
  int sv  = tid>>2;
  int c8u = (tid&3)*8;
  int av = v0 + sv;
  int d = av/784; int rm2 = av - d*784; int hh = rm2/28; int ww = rm2 - hh*28;
  int pbase = (d*30 + hh)*30 + ww;
  int lane = tid&63, wv = tid>>6;
  int lm = lane&15, lq = lane>>4;
  int mbase = (wv>>1)*32;
  int nbase = (wv&1)*(COUT/2);

  float4v acc[2][NT];
  #pragma unroll
  for (int mt=0; mt<2; mt++)
    #pragma unroll
    for (int nt=0; nt<NT; nt++) acc[mt][nt] = (float4v)0.f;

  uint4 a_r;
  uint2 b_r[NB8];
  auto load_s = [&](int s){
    int tp = s/CH, cc = s - tp*CH;
    int td = tp/9, tr = tp - td*9, th = tr/3, tw = tr - th*3;
    int toff = td*900 + th*30 + tw;
    a_r = *(const uint4*)(xp + (size_t)(pbase + toff)*CIN + cc*32 + c8u);
    #pragma unroll
    for (int j=0;j<NB8;j++){
      int bi = tid + j*256;
      int n = bi>>3, c4 = (bi&7)*4;
      b_r[j] = *(const uint2*)(wtb + (size_t)n*K + s*32 + c4);
    }
  };
  auto write_s = [&](int buf){
    *(uint4*)(&As[buf][sv*40 + c8u]) = a_r;
    #pragma unroll
    for (int j=0;j<NB8;j++){
      int bi = tid + j*256;
      int n = bi>>3, c4 = (bi&7)*4;
      *(uint2*)(&Bs[buf][n*40 + c4]) = b_r[j];
    }
  };

  load_s(0);
  write_s(0);
  __syncthreads();
  for (int s = 0; s < STEPS; s++){
    if (s+1 < STEPS) load_s(s+1);
    int buf = s&1;
    short8 aa[2], bb[NT];
    #pragma unroll
    for (int mt=0; mt<2; mt++)
      aa[mt] = *(const short8*)(&As[buf][(mbase + mt*16 + lm)*40 + lq*8]);
    #pragma unroll
    for (int nt=0; nt<NT; nt++)
      bb[nt] = *(const short8*)(&Bs[buf][(nbase + nt*16 + lm)*40 + lq*8]);
    #pragma unroll
    for (int nt=0; nt<NT; nt++)
      #pragma unroll
      for (int mt=0; mt<2; mt++)
        acc[mt][nt] = __builtin_amdgcn_mfma_f32_16x16x32_bf16(aa[mt], bb[nt], acc[mt][nt], 0, 0, 0);
    if (s+1 < STEPS) write_s((s+1)&1);
    __syncthreads();
  }
  #pragma unroll
  for (int mt=0; mt<2; mt++)
    #pragma unroll
    for (int nt=0; nt<NT; nt++)
      #pragma unroll
      for (int r=0; r<4; r++){
        int row = v0 + mbase + mt*16 + lq*4 + r;
        int col = nbase + nt*16 + lm;
        out[(size_t)row*COUT + col] = acc[mt][nt][r];
      }
}

// ---- generic MFMA GEMM; MRG=1 adds a second pointer set for the f-half ----
template<int K, int NF, int GATHER, int ASRC, int EPI, int MRG>
__global__ __launch_bounds__(256) void k_gemm(const float* __restrict__ Af,
                                              const u16* __restrict__ Ab,
                                              const u16* __restrict__ B,
                                              const float* __restrict__ bias,
                                              const float* __restrict__ resid,
                                              float* __restrict__ outf,
                                              u16* __restrict__ out16,
                                              u16* __restrict__ out16b,
                                              float scale,
                                              const u16* __restrict__ B2,
                                              const float* __restrict__ bias2,
                                              const float* __restrict__ resid2,
                                              float* __restrict__ outf2,
                                              u16* __restrict__ out162,
                                              u16* __restrict__ out16b2){
  constexpr int STEPS = K/32;
  constexpr int NB = NF/64;
  __shared__ __align__(16) u16 As[2][64*40];
  __shared__ __align__(16) u16 Bs[2][64*40];
  __shared__ int map[64];
  int tid = threadIdx.x;
  int bid = blockIdx.x;
  int mb = bid / NB, nb = bid - mb*NB;
  int v0 = mb*64, ncol0 = nb*64;
  int half = (MRG && v0 >= LTOT) ? 1 : 0;
  const u16* Bx = half ? B2 : B;
  const float* biasx = half ? bias2 : bias;
  const float* residx = half ? resid2 : resid;
  float* outfx = half ? outf2 : outf;
  u16* out16x = half ? out162 : out16;
  u16* out16bx = half ? out16b2 : out16b;
  int vloc = v0 - half*LTOT;
  if (tid < 64){
    int r = vloc + tid;
    int src;
    if (GATHER == 0){
      src = r;
    } else if (GATHER == 1){
      int w = r/343; int n = r - w*343;
      int nd = w>>4, nh = (w>>2)&3, nw = w&3;
      int i = n/49; int rr = n - i*49; int j = rr/7; int k2 = rr - j*7;
      int dd = nd*7 + i + 3; if (dd >= 28) dd -= 28;
      int hh = nh*7 + j + 3; if (hh >= 28) hh -= 28;
      int ww = nw*7 + k2 + 3; if (ww >= 28) ww -= 28;
      src = (dd*28 + hh)*28 + ww;
    } else {
      int l = r;
      int d = l/784; int rm = l - d*784; int y = rm/28; int x = rm - y*28;
      int dp = d-3; if (dp<0) dp+=28;
      int yp = y-3; if (yp<0) yp+=28;
      int xq = x-3; if (xq<0) xq+=28;
      int nd = dp/7, i = dp - nd*7;
      int nh = yp/7, j = yp - nh*7;
      int nw = xq/7, k2 = xq - nw*7;
      src = ((nd*4+nh)*4+nw)*NTOK + (i*7+j)*7 + k2;
    }
    map[tid] = src + half*LTOT;     // A is contiguous across halves
  }
  __syncthreads();
  int sv = tid>>2, c8 = (tid&3)*8;
  int arow = map[sv];
  int lane = tid&63, wv = tid>>6;
  int lm = lane&15, lq = lane>>4;
  int mbase = (wv>>1)*32, nbase = (wv&1)*32;

  float4v acc[2][2];
  #pragma unroll
  for (int mt=0; mt<2; mt++)
    #pragma unroll
    for (int nt=0; nt<2; nt++) acc[mt][nt] = (float4v)0.f;

  float4 afr0, afr1; uint4 abr; uint4 bvr;
  auto load_s = [&](int s){
    if (ASRC == 0){
      const float* ap = Af + (size_t)arow*K + s*32 + c8;
      afr0 = *(const float4*)ap;
      afr1 = *(const float4*)(ap+4);
    } else {
      abr = *(const uint4*)(Ab + (size_t)arow*K + s*32 + c8);
    }
    bvr = *(const uint4*)(Bx + (size_t)(ncol0 + sv)*K + s*32 + c8);
  };
  auto write_s = [&](int buf){
    if (ASRC == 0){
      uint4 pk;
      pk.x = (u32)f2b(afr0.x) | ((u32)f2b(afr0.y)<<16);
      pk.y = (u32)f2b(afr0.z) | ((u32)f2b(afr0.w)<<16);
      pk.z = (u32)f2b(afr1.x) | ((u32)f2b(afr1.y)<<16);
      pk.w = (u32)f2b(afr1.z) | ((u32)f2b(afr1.w)<<16);
      *(uint4*)(&As[buf][sv*40 + c8]) = pk;
    } else {
      *(uint4*)(&As[buf][sv*40 + c8]) = abr;
    }
    *(uint4*)(&Bs[buf][sv*40 + c8]) = bvr;
  };

  load_s(0);
  write_s(0);
  __syncthreads();
  for (int s = 0; s < STEPS; s++){
    if (s+1 < STEPS) load_s(s+1);
    int buf = s&1;
    short8 aa[2], bb[2];
    #pragma unroll
    for (int mt=0; mt<2; mt++)
      aa[mt] = *(const short8*)(&As[buf][(mbase + mt*16 + lm)*40 + lq*8]);
    #pragma unroll
    for (int nt=0; nt<2; nt++)
      bb[nt] = *(const short8*)(&Bs[buf][(nbase + nt*16 + lm)*40 + lq*8]);
    #pragma unroll
    for (int nt=0; nt<2; nt++)
      #pragma unroll
      for (int mt=0; mt<2; mt++)
        acc[mt][nt] = __builtin_amdgcn_mfma_f32_16x16x32_bf16(aa[mt], bb[nt], acc[mt][nt], 0, 0, 0);
    if (s+1 < STEPS) write_s((s+1)&1);
    __syncthreads();
  }
  // epilogue
  float bv[2];
  #pragma unroll
  for (int nt=0; nt<2; nt++) bv[nt] = biasx ? biasx[ncol0 + nbase + nt*16 + lm] : 0.f;
  #pragma unroll
  for (int mt=0; mt<2; mt++){
    #pragma unroll
    for (int r=0; r<4; r++){
      int row = v0 + mbase + mt*16 + lq*4 + r;
      int rowl = row - half*LTOT;
      if (EPI == 0 || EPI == 3){
        int w = rowl/343; int tok = rowl - w*343;
        #pragma unroll
        for (int nt=0; nt<2; nt++){
          int col = ncol0 + nbase + nt*16 + lm;
          float val = (acc[mt][nt][r] + bv[nt]) * scale;
          if (EPI == 0){
            int h = col>>5, c = col&31;
            out16x[((size_t)(w*6 + h)*343 + tok)*32 + c] = f2b(val);
          } else {
            u16* dst = (col < 192) ? out16x : out16bx;
            int cc = (col < 192) ? col : col - 192;
            int h = cc>>5, c = cc&31;
            dst[((size_t)(w*6 + h)*343 + tok)*32 + c] = f2b(val);
          }
        }
      } else if (EPI == 1){
        #pragma unroll
        for (int nt=0; nt<2; nt++){
          int col = ncol0 + nbase + nt*16 + lm;
          size_t o = (size_t)rowl*NF + col;
          outfx[o] = acc[mt][nt][r] + bv[nt] + residx[o];
        }
      } else {
        #pragma unroll
        for (int nt=0; nt<2; nt++){
          int col = ncol0 + nbase + nt*16 + lm;
          float v = acc[mt][nt][r] + bv[nt];
          float gl = 0.5f*v*(1.f + erff(v*0.70710678118f));
          out16[(size_t)row*NF + col] = f2b(gl);   // fc1: single global hs
        }
      }
    }
  }
}

// ---- BN stats, merged m+f: grid 128, x = contiguous [2L][C] ---------------
__global__ __launch_bounds__(192) void k_bnsum(const float* __restrict__ x, int C,
                                               float* __restrict__ psum){
  int bid = blockIdx.x, t = threadIdx.x;
  int rpi = 192/C;
  int c  = (C==192) ? t : (t % 96);
  int ro = (C==192) ? 0 : (t / 96);
  float s=0.f, s2=0.f;
  int base = bid*343;
  for (int r = ro; r < 343; r += rpi){
    float v = x[(size_t)(base+r)*C + c];
    s += v; s2 += v*v;
  }
  psum[(size_t)bid*384 + t]       = s;
  psum[(size_t)bid*384 + 192 + t] = s2;
}
__global__ void k_bnfin2(const float* __restrict__ psum, int C,
                         const float* __restrict__ g0, const float* __restrict__ bb0,
                         const float* __restrict__ g1, const float* __restrict__ bb1,
                         float* a0, float* b0o, float* a1, float* b1o){
  int h = blockIdx.x;
  int c = threadIdx.x;
  if (c >= C) return;
  const float* g  = h ? g1 : g0;
  const float* bb = h ? bb1 : bb0;
  float* ao = h ? a1 : a0;
  float* bo = h ? b1o : b0o;
  const float* ps = psum + (size_t)h*64*384;
  int slots = 192/C;
  float s=0.f, s2=0.f;
  for (int b=0; b<64; b++)
    for (int k=0; k<slots; k++){
      s  += ps[(size_t)b*384 + k*C + c];
      s2 += ps[(size_t)b*384 + 192 + k*C + c];
    }
  float mu = s/(float)LTOT;
  float var = s2/(float)LTOT - mu*mu;
  float rstd = rsqrtf(var + 1e-5f);
  float aa = rstd * g[c];
  ao[c] = aa;
  bo[c] = bb[c] - mu*aa;
}

// ------------- conv3 1x1x1 merged m+f: grid 2L -----------------------------
__global__ __launch_bounds__(96) void k_flow(const float* __restrict__ t2,
                                             const float* __restrict__ a2b,
                                             const float* __restrict__ w3m,
                                             const float* __restrict__ w3f,
                                             float* __restrict__ flow){
  __shared__ float xr[96];
  int l = blockIdx.x; int t = threadIdx.x;
  int half = l >= LTOT; int ll = l - half*LTOT;
  const float* a2 = a2b + half*192; const float* b2 = a2 + 96;
  const float* w3 = half ? w3f : w3m;
  float xv = t2[(size_t)l*96 + t];
  xr[t] = fmaxf(xv*a2[t] + b2[t], 0.f);
  __syncthreads();
  if (t < 18){
    float acc = 0.f;
    for (int c=0;c<96;c++) acc += xr[c]*w3[t*96 + c];
    flow[((size_t)half*18 + t)*LTOT + ll] = acc;
  }
}

// ------------- trilinear warp merged m+f: grid 2L --------------------------
__global__ __launch_bounds__(192) void k_warp(const float* __restrict__ src,
                                              const float* __restrict__ flow, float* __restrict__ dst){
  int l = blockIdx.x; int tid = threadIdx.x; int hh = tid>>5;
  int half = l >= LTOT; int ll = l - half*LTOT;
  const float* s_ = src + (size_t)half*LTOT*192;
  int d = ll/784; int rm = ll - d*784; int y = rm/28; int x = rm - y*28;
  float fd = flow[((size_t)half*18 + hh*3+0)*LTOT + ll];
  float fy = flow[((size_t)half*18 + hh*3+1)*LTOT + ll];
  float fx = flow[((size_t)half*18 + hh*3+2)*LTOT + ll];
  float cd = fminf(fmaxf((float)d + fd, 0.f), 27.f);
  float cy = fminf(fmaxf((float)y + fy, 0.f), 27.f);
  float cx = fminf(fmaxf((float)x + fx, 0.f), 27.f);
  int d0 = (int)floorf(cd); int d1 = min(d0+1, 27);
  int y0 = (int)floorf(cy); int y1 = min(y0+1, 27);
  int x0 = (int)floorf(cx); int x1 = min(x0+1, 27);
  float wd = cd - (float)d0, wy = cy - (float)y0, wx = cx - (float)x0;
  #define SMP(di,yi,xi) s_[(size_t)(((di)*28+(yi))*28+(xi))*192 + tid]
  float v000 = SMP(d0,y0,x0), v001 = SMP(d0,y0,x1), v010 = SMP(d0,y1,x0), v011 = SMP(d0,y1,x1);
  float v100 = SMP(d1,y0,x0), v101 = SMP(d1,y0,x1), v110 = SMP(d1,y1,x0), v111 = SMP(d1,y1,x1);
  #undef SMP
  float o = v000*(1-wd)*(1-wy)*(1-wx) + v001*(1-wd)*(1-wy)*wx
          + v010*(1-wd)*wy*(1-wx)     + v011*(1-wd)*wy*wx
          + v100*wd*(1-wy)*(1-wx)     + v101*wd*(1-wy)*wx
          + v110*wd*wy*(1-wx)         + v111*wd*wy*wx;
  dst[(size_t)l*192 + tid] = o;
}

// ------------ MFMA attention, qg merged 3-way: grid 1536 -------------------
// Block = (dir, wh, qg2 in {0,1}); stages K/V ONCE, runs 3 q-rounds
// (qt = qg2*12 + r*4 + wv).  Cuts K/V staging redundancy 6x -> 2x and
// dispatch rounds 9 -> 3.0 (512 resident at 61KB LDS).
__global__ __launch_bounds__(256) void k_attmfma(const u16* __restrict__ Q1,
                                                 const u16* __restrict__ K1,
                                                 const u16* __restrict__ V1,
                                                 const u16* __restrict__ Q2,
                                                 const u16* __restrict__ K2,
                                                 const u16* __restrict__ V2,
                                                 const float* __restrict__ bm,
                                                 float* __restrict__ ctx1,
                                                 float* __restrict__ ctx2){
  __shared__ __align__(16) u16 Kl[352*40];      // [key][40]
  __shared__ __align__(16) u16 Vt[32*360];      // [dim][360]
  __shared__ __align__(16) u16 Pl[4][2][16*40]; // per-wave, dbuf
  int bid0 = blockIdx.x;                        // [0, 1536)
  int halfsel = bid0 >= 768;
  int bid = bid0 - halfsel*768;                 // [0, 768)
  int wh = bid >> 1;                            // [0, 384)
  int qg2 = bid & 1;                            // q half: tiles 0-11 / 12-21
  const u16* Q = halfsel ? Q2 : Q1;
  const u16* K = halfsel ? K2 : K1;
  const u16* V = halfsel ? V2 : V1;
  float* ctx = halfsel ? ctx2 : ctx1;
  int w = wh/6, h = wh - w*6;
  int tid = threadIdx.x;
  int nd = w>>4, nh = (w>>2)&3, nw = w&3;
  int type = ((nd==3)?4:0) | ((nh==3)?2:0) | ((nw==3)?1:0);
  const u16* kb = K + (size_t)wh*10976;
  const u16* vbp = V + (size_t)wh*10976;
  for (int idx=tid; idx<343*4; idx+=256){
    int row = idx>>2, c8 = (idx&3)*8;
    uint4 val = *(const uint4*)(kb + row*32 + c8);
    *(uint4*)(&Kl[row*40 + c8]) = val;
  }
  for (int idx=tid; idx<9*40; idx+=256) Kl[343*40 + idx] = 0;
  for (int idx=tid; idx<343*4; idx+=256){
    int row = idx>>2, c8 = (idx&3)*8;
    uint4 val = *(const uint4*)(vbp + row*32 + c8);
    const u16* pv = (const u16*)&val;
    #pragma unroll
    for (int j=0;j<8;j++) Vt[(c8+j)*360 + row] = pv[j];
  }
  for (int idx=tid; idx<32*17; idx+=256){
    int dd = idx/17, cc = 343 + idx - (idx/17)*17;
    Vt[dd*360 + cc] = 0;
  }
  __syncthreads();
  int lane = tid&63, wv = tid>>6;
  int lm = lane&15, lq = lane>>4;
  const float* bmh = bm + (size_t)(type*6 + h)*123904;
  for (int rnd = 0; rnd < 3; rnd++){
    int qt = qg2*12 + rnd*4 + wv;
    if (qt < 22){
      int q0 = qt*16;
      short8 bq = *(const short8*)(Q + (size_t)wh*10976 + (q0+lm)*32 + lq*8);
      float4v sc[22];
      #pragma unroll
      for (int kt=0; kt<22; kt++){
        short8 ak = *(const short8*)(&Kl[(kt*16+lm)*40 + lq*8]);
        sc[kt] = __builtin_amdgcn_mfma_f32_16x16x32_bf16(ak, bq, (float4v)0.f, 0, 0, 0);
      }
      const float* bcol = bmh + q0 + lm;
      float mx = -3.0e38f;
      #pragma unroll
      for (int kt=0; kt<22; kt++){
        #pragma unroll
        for (int r=0; r<4; r++){
          int key = kt*16 + lq*4 + r;
          float s = sc[kt][r] + bcol[(size_t)key*352];
          sc[kt][r] = s;
          mx = fmaxf(mx, s);
        }
      }
      mx = fmaxf(mx, __shfl_xor(mx, 16));
      mx = fmaxf(mx, __shfl_xor(mx, 32));
      float sm = 0.f;
      #pragma unroll
      for (int kt=0; kt<22; kt++){
        #pragma unroll
        for (int r=0; r<4; r++){
          float p = __expf(sc[kt][r] - mx);
          sc[kt][r] = p;
          sm += p;
        }
      }
      sm += __shfl_xor(sm, 16);
      sm += __shfl_xor(sm, 32);
      float inv = 1.f/sm;
      float4v o0 = (float4v)0.f, o1 = (float4v)0.f;
      #pragma unroll
      for (int s=0; s<11; s++){
        u16* pw = &Pl[wv][s&1][0];
        #pragma unroll
        for (int hf=0; hf<2; hf++){
          int kt = 2*s + hf;
          uint2 pv2;
          pv2.x = (u32)f2b(sc[kt][0]) | ((u32)f2b(sc[kt][1])<<16);
          pv2.y = (u32)f2b(sc[kt][2]) | ((u32)f2b(sc[kt][3])<<16);
          *(uint2*)(&pw[lm*40 + hf*16 + lq*4]) = pv2;
        }
        short8 bp = *(const short8*)(&pw[lm*40 + lq*8]);
        short8 a0 = *(const short8*)(&Vt[lm*360 + s*32 + lq*8]);
        short8 a1 = *(const short8*)(&Vt[(16+lm)*360 + s*32 + lq*8]);
        o0 = __builtin_amdgcn_mfma_f32_16x16x32_bf16(a0, bp, o0, 0, 0, 0);
        o1 = __builtin_amdgcn_mfma_f32_16x16x32_bf16(a1, bp, o1, 0, 0, 0);
      }
      int query = q0 + lm;
      if (query < 343){
        float* ob = ctx + ((size_t)w*NTOK + query)*192 + h*32;
        float4 t0, t1v;
        t0.x = o0[0]*inv; t0.y = o0[1]*inv; t0.z = o0[2]*inv; t0.w = o0[3]*inv;
        t1v.x = o1[0]*inv; t1v.y = o1[1]*inv; t1v.z = o1[2]*inv; t1v.w = o1[3]*inv;
        *(float4*)(ob + lq*4) = t0;
        *(float4*)(ob + 16 + lq*4) = t1v;
      }
    }
  }
}

// ===========================================================================
extern "C" void kernel_launch(void* const* d_in, const int* in_sizes, int n_in,
                              void* d_out, int out_size, void* d_ws, size_t ws_size,
                              hipStream_t stream){
  const float* mov     = (const float*)d_in[0];
  const float* fix     = (const float*)d_in[1];
  const float* n1g     = (const float*)d_in[2];
  const float* n1b     = (const float*)d_in[3];
  const float* offm_w1 = (const float*)d_in[4];
  const float* offm_g1 = (const float*)d_in[5];
  const float* offm_b1 = (const float*)d_in[6];
  const float* offm_w2 = (const float*)d_in[7];
  const float* offm_g2 = (const float*)d_in[8];
  const float* offm_b2 = (const float*)d_in[9];
  const float* offm_w3 = (const float*)d_in[10];
  const float* offf_w1 = (const float*)d_in[11];
  const float* offf_g1 = (const float*)d_in[12];
  const float* offf_b1 = (const float*)d_in[13];
  const float* offf_w2 = (const float*)d_in[14];
  const float* offf_g2 = (const float*)d_in[15];
  const float* offf_b2 = (const float*)d_in[16];
  const float* offf_w3 = (const float*)d_in[17];
  const float* mq_w    = (const float*)d_in[18];
  const float* mkv_w   = (const float*)d_in[19];
  const float* fq_w    = (const float*)d_in[20];
  const float* fkv_w   = (const float*)d_in[21];
  const float* mproj_w = (const float*)d_in[22];
  const float* fproj_w = (const float*)d_in[23];
  const float* mq_b    = (const float*)d_in[24];
  const float* mkv_b   = (const float*)d_in[25];
  const float* fq_b    = (const float*)d_in[26];
  const float* fkv_b   = (const float*)d_in[27];
  const float* mproj_b = (const float*)d_in[28];
  const float* fproj_b = (const float*)d_in[29];
  const float* rpbt    = (const float*)d_in[30];
  const float* n2g     = (const float*)d_in[31];
  const float* n2b     = (const float*)d_in[32];
  const float* fc1_w   = (const float*)d_in[33];
  const float* fc1_b   = (const float*)d_in[34];
  const float* fc2_w   = (const float*)d_in[35];
  const float* fc2_b   = (const float*)d_in[36];
  float* outp = (float*)d_out;

  float* W = (float*)d_ws;
  const size_t L192 = (size_t)LTOT*192;   // floats per region (16.86 MB)
  // conv-phase layout:
  float* m_   = W;                         // region 0
  float* f_   = W + 1*L192;                // region 1
  float* t1   = W + 2*L192;                // regions 2,3 ([2L][192])
  u16* xp     = (u16*)(W + 4*L192);        // 27000*384 u16
  u16* xp2    = xp + (size_t)27000*384;    // 54000*192 u16, contiguous m|f
  float* sb   = W + 6*L192 + 3000000;      // stats block
  float* a1m = sb,       *b1m = sb+192;
  float* a1f = sb+384,   *b1f = sb+576;
  float* a2m = sb+768,   *b2m = sb+864;
  float* a2f = sb+960,   *b2f = sb+1056;
  float* psum = sb + 1536;                 // 128*384 floats
  float* flowm = W + 6*L192 + 3100000;     // [36][LTOT]
  float* t2   = W + 7*L192;                // [2L][96]
  u16* wt1m = (u16*)(W + 8*L192);          // conv weights, region 8
  u16* wt1f = wt1m + 192*10368;
  u16* wt2m = wt1f + 192*10368;
  u16* wt2f = wt2m + 96*5184;
  // post-conv reuse:
  float* dmov = W + 4*L192;                // region 4
  float* dfix = W + 5*L192;                // region 5
  float* ctxm = dmov; float* ctxf = dfix;
  float* mout = m_;   float* fout = f_;
  u16* QMb = (u16*)(W + 6*L192);
  u16* QFb = (u16*)(W + 7*L192);
  u16* Kmb = (u16*)(W + 2*L192);
  u16* Vmb = (u16*)(W + 3*L192);
  u16* Kfb = (u16*)(W + 8*L192);
  u16* Vfb = (u16*)(W + 9*L192);
  float* bm = W;
  u16* wq_m  = (u16*)(W + 9*L192) + 4214784;
  u16* wq_f  = wq_m  + 36864;
  u16* wkv_m = wq_f  + 36864;
  u16* wkv_f = wkv_m + 73728;
  u16* wpj_m = wkv_f + 73728;
  u16* wpj_f = wpj_m + 36864;
  u16* wfc1  = wpj_f + 36864;
  u16* wfc2  = wfc1  + 147456;
  u16* hs16  = (u16*)(W + 2*L192);         // [2L][768] regions 2-5
  float* lnbuf = W + 6*L192;               // [2L][192] regions 6,7

  // weight prep (3 launches)
  k_prepw1b<<<(2*192*10368+255)/256, 256, 0, stream>>>(offm_w1, offf_w1, wt1m, wt1f);
  k_prepw2b<<<(2*96*5184+255)/256, 256, 0, stream>>>(offm_w2, offf_w2, wt2m, wt2f);
  k_prepwb8<<<2304, 256, 0, stream>>>(mq_w, fq_w, mkv_w, fkv_w, mproj_w, fproj_w, fc1_w, fc2_w,
                                      wq_m, wq_f, wkv_m, wkv_f, wpj_m, wpj_f, wfc1, wfc2);
  // layernorm1
  k_ln<<<2*LTOT, 64, 0, stream>>>(mov, fix, n1g, n1b, m_, f_);
  // padded bf16 volume [m|f]
  k_pad1<<<27000, 192, 0, stream>>>(m_, f_, xp);
  // conv1 (r7 winner: 4-wave 64x48, tri-buffered, counted vmcnt)
  k_conv1dma<<<686, 256, 0, stream>>>(xp, wt1m, wt1f, t1, t1 + 2*L192);
  k_bnsum<<<128, 192, 0, stream>>>(t1, 192, psum);
  k_bnfin2<<<2, 192, 0, stream>>>(psum, 192, offm_g1, offm_b1, offf_g1, offf_b1, a1m, b1m, a1f, b1f);
  k_pad2<<<54000, 192, 0, stream>>>(t1, sb, xp2);
  // conv2 (m+f halves of contiguous xp2)
  k_convmfma<192,96><<<686, 256, 0, stream>>>(xp2, xp2 + (size_t)27000*192, wt2m, wt2f,
                                              t2, t2 + (size_t)LTOT*96);
  k_bnsum<<<128, 192, 0, stream>>>(t2, 96, psum);
  k_bnfin2<<<2, 96, 0, stream>>>(psum, 96, offm_g2, offm_b2, offf_g2, offf_b2, a2m, b2m, a2f, b2f);
  k_flow<<<2*LTOT, 96, 0, stream>>>(t2, sb+768, offm_w3, offf_w3, flowm);
  // deformable warp (merged)
  k_warp<<<2*LTOT, 192, 0, stream>>>(m_, flowm, dmov);
  // windowed projections (merged m+f)
  const float scale = 0.17677669529663687f; // 32^-0.5
  k_gemm<192,192,1,0,0,1><<<2*343*3, 256, 0, stream>>>(dmov, nullptr, wq_m, mq_b, nullptr, nullptr, QMb, nullptr, scale,
                                                       wq_f, fq_b, nullptr, nullptr, QFb, nullptr);
  k_gemm<192,384,1,0,3,1><<<2*343*6, 256, 0, stream>>>(m_, nullptr, wkv_m, mkv_b, nullptr, nullptr, Kmb, Vmb, 1.f,
                                                       wkv_f, fkv_b, nullptr, nullptr, Kfb, Vfb);
  // bias matrix (m_/f_ now dead)
  k_prepbias<<<(48*123904+255)/256, 256, 0, stream>>>(rpbt, bm);
  // attention merged (qg 3-way): mo = attend(dfQ, mK, mV); fo = attend(dmQ, fK, fV)
  k_attmfma<<<1536, 256, 0, stream>>>(QFb, Kmb, Vmb, QMb, Kfb, Vfb, bm, ctxm, ctxf);
  // proj + residual + window-reverse (merged)
  k_gemm<192,192,2,0,1,1><<<2*343*3, 256, 0, stream>>>(ctxm, nullptr, wpj_m, mproj_b, mov, mout, nullptr, nullptr, 1.f,
                                                       wpj_f, fproj_b, fix, fout, nullptr, nullptr);
  // MLP both halves (contiguous rows)
  k_ln1<<<2*LTOT, 64, 0, stream>>>(mout, n2g, n2b, lnbuf);
  k_gemm<192,768,0,0,2,0><<<2*343*12, 256, 0, stream>>>(lnbuf, nullptr, wfc1, fc1_b, nullptr, nullptr, hs16, nullptr, 1.f,
                                                        nullptr, nullptr, nullptr, nullptr, nullptr, nullptr);
  k_gemm<768,192,0,1,1,0><<<2*343*3, 256, 0, stream>>>(nullptr, hs16, wfc2, fc2_b, mout, outp, nullptr, nullptr, 1.f,
                                                       nullptr, nullptr, nullptr, nullptr, nullptr, nullptr);
}

// Round 11
// 1184.518 us; speedup vs baseline: 1.1567x; 1.0067x over previous
//
#include <hip/hip_runtime.h>

#define LTOT 21952      // 28^3
#define NTOK 343        // 7^3

typedef unsigned short u16;
typedef unsigned int   u32;
typedef __attribute__((ext_vector_type(8))) short short8;
typedef __attribute__((ext_vector_type(4))) float float4v;

__device__ __forceinline__ u16 f2b(float f){
  u32 x = __float_as_uint(f);
  u32 r = (x + 0x7fffu + ((x>>16)&1u)) >> 16;
  return (u16)r;
}

// 16B global -> LDS direct DMA (HW dest = wave-uniform base + lane*16)
__device__ __forceinline__ void dma16(const u16* g, u16* l){
  __builtin_amdgcn_global_load_lds((const __attribute__((address_space(1))) u32*)g,
                                   (__attribute__((address_space(3))) u32*)l,
                                   16, 0, 0);
}

// ---------------- LayerNorm (norm1) : f32 in -> f32 out --------------------
__global__ __launch_bounds__(64) void k_ln(const float* __restrict__ mov, const float* __restrict__ fix,
                                           const float* __restrict__ g, const float* __restrict__ b,
                                           float* __restrict__ om, float* __restrict__ of){
  int row = blockIdx.x;
  const float* src; float* dst;
  if (row < LTOT){ src = mov + (size_t)row*192; dst = om + (size_t)row*192; }
  else          { src = fix + (size_t)(row-LTOT)*192; dst = of + (size_t)(row-LTOT)*192; }
  int t = threadIdx.x;
  float x0 = src[t], x1 = src[t+64], x2 = src[t+128];
  float s = x0+x1+x2, s2 = x0*x0 + x1*x1 + x2*x2;
  for (int o=32;o;o>>=1){ s += __shfl_xor(s,o); s2 += __shfl_xor(s2,o); }
  float mu = s*(1.f/192.f);
  float var = s2*(1.f/192.f) - mu*mu;
  float rs = rsqrtf(var + 1e-5f);
  dst[t]     = (x0-mu)*rs*g[t]     + b[t];
  dst[t+64]  = (x1-mu)*rs*g[t+64]  + b[t+64];
  dst[t+128] = (x2-mu)*rs*g[t+128] + b[t+128];
}

// ---------------- LayerNorm (norm2), single buffer, rows may span 2L -------
__global__ __launch_bounds__(64) void k_ln1(const float* __restrict__ x,
                                            const float* __restrict__ g, const float* __restrict__ b,
                                            float* __restrict__ y){
  int row = blockIdx.x;
  const float* src = x + (size_t)row*192;
  float* dst = y + (size_t)row*192;
  int t = threadIdx.x;
  float x0 = src[t], x1 = src[t+64], x2 = src[t+128];
  float s = x0+x1+x2, s2 = x0*x0 + x1*x1 + x2*x2;
  for (int o=32;o;o>>=1){ s += __shfl_xor(s,o); s2 += __shfl_xor(s2,o); }
  float mu = s*(1.f/192.f);
  float var = s2*(1.f/192.f) - mu*mu;
  float rs = rsqrtf(var + 1e-5f);
  dst[t]     = (x0-mu)*rs*g[t]     + b[t];
  dst[t+64]  = (x1-mu)*rs*g[t+64]  + b[t+64];
  dst[t+128] = (x2-mu)*rs*g[t+128] + b[t+128];
}

// ------ conv1 weight prep (m+f merged): f32 -> w1t[s][wv][192][8] bf16 -----
__global__ void k_prepw1b(const float* __restrict__ sm, const float* __restrict__ sf,
                          u16* __restrict__ dm, u16* __restrict__ df){
  int idx = blockIdx.x*256 + threadIdx.x;
  if (idx >= 2*192*10368) return;
  int half = idx >= 192*10368;
  int i = idx - half*192*10368;
  const float* src = half ? sf : sm;
  u16* dst = half ? df : dm;
  int swap = half ? 192 : 0;
  int c8 = i & 7;
  int t2 = i >> 3;
  int n  = t2 % 192;
  int sw = t2 / 192;
  int k  = (sw>>2)*32 + (sw&3)*8 + c8;
  int t  = k / 384; int c = k - t*384;
  int cs = c + swap; if (cs >= 384) cs -= 384;
  dst[i] = f2b(src[((size_t)n*384 + cs)*27 + t]);
}
// ------ conv2 weight prep (m+f merged): (96,192,27) -> [n][t*192+c] --------
__global__ void k_prepw2b(const float* __restrict__ sm, const float* __restrict__ sf,
                          u16* __restrict__ dm, u16* __restrict__ df){
  int idx = blockIdx.x*256 + threadIdx.x;
  if (idx >= 2*96*5184) return;
  int half = idx >= 96*5184;
  int i = idx - half*96*5184;
  const float* src = half ? sf : sm;
  u16* dst = half ? df : dm;
  int n = i / 5184; int k = i - n*5184;
  int t = k / 192; int c = k - t*192;
  dst[i] = f2b(src[((size_t)n*192 + c)*27 + t]);
}
// ------ all 8 GEMM weight copies in one launch -----------------------------
__global__ void k_prepwb8(const float* s0,const float* s1,const float* s2,const float* s3,
                          const float* s4,const float* s5,const float* s6,const float* s7,
                          u16* d0,u16* d1,u16* d2,u16* d3,u16* d4,u16* d5,u16* d6,u16* d7){
  int idx = blockIdx.x*256 + threadIdx.x;
  if      (idx < 36864)  d0[idx]        = f2b(s0[idx]);
  else if (idx < 73728)  d1[idx-36864]  = f2b(s1[idx-36864]);
  else if (idx < 147456) d2[idx-73728]  = f2b(s2[idx-73728]);
  else if (idx < 221184) d3[idx-147456] = f2b(s3[idx-147456]);
  else if (idx < 258048) d4[idx-221184] = f2b(s4[idx-221184]);
  else if (idx < 294912) d5[idx-258048] = f2b(s5[idx-258048]);
  else if (idx < 442368) d6[idx-294912] = f2b(s6[idx-294912]);
  else if (idx < 589824) d7[idx-442368] = f2b(s7[idx-442368]);
}

// ------ bias matrix prep: [type 8][head 6][key 352][query 352] f32 ---------
__global__ void k_prepbias(const float* __restrict__ rpt, float* __restrict__ bm){
  int idx = blockIdx.x*256 + threadIdx.x;
  if (idx >= 48*123904) return;
  int th = idx / 123904; int r = idx - th*123904;
  int key = r / 352; int q = r - key*352;
  int type = th / 6; int h = th - type*6;
  float v;
  if (key >= 343 || q >= 343){
    v = -30000.f;
  } else {
    int ki = key/49, kj = (key/7)%7, kk = key%7;
    int qi = q/49,   qj = (q/7)%7,   qk = q%7;
    int ridx = ((qi-ki+6)*13 + (qj-kj+6))*13 + (qk-kk+6);
    float rv = rpt[ridx*6 + h];
    int bd = (type>>2)&1, bh = (type>>1)&1, bw = type&1;
    int lq_ = (bd?((qi<4)?1:2):0)*9 + (bh?((qj<4)?1:2):0)*3 + (bw?((qk<4)?1:2):0);
    int lk_ = (bd?((ki<4)?1:2):0)*9 + (bh?((kj<4)?1:2):0)*3 + (bw?((kk<4)?1:2):0);
    v = rv + ((lq_==lk_) ? 0.f : -100.f);
  }
  bm[idx] = v;
}

// ------ padded volume builders (30^3, zero borders), bf16 ------------------
__global__ __launch_bounds__(192) void k_pad1(const float* __restrict__ m_, const float* __restrict__ f_,
                                              u16* __restrict__ xp){
  int p = blockIdx.x; int t = threadIdx.x;
  int pd = p/900; int r = p - pd*900; int ph = r/30; int pw = r - ph*30;
  int d = pd-1, h = ph-1, w = pw-1;
  u16 vm = 0, vf = 0;
  if ((unsigned)d < 28u && (unsigned)h < 28u && (unsigned)w < 28u){
    size_t l = (size_t)((d*28+h)*28+w)*192 + t;
    vm = f2b(m_[l]); vf = f2b(f_[l]);
  }
  xp[(size_t)p*384 + t] = vm;
  xp[(size_t)p*384 + 192 + t] = vf;
}
// pad2 merged m+f: grid 54000; xp2 contiguous [54000][192]
__global__ __launch_bounds__(192) void k_pad2(const float* __restrict__ t1,
                                              const float* __restrict__ sb_,
                                              u16* __restrict__ xp2){
  int p = blockIdx.x; int t = threadIdx.x;
  int half = (p >= 27000); int pl = p - half*27000;
  const float* a1 = sb_ + half*384; const float* b1 = a1 + 192;
  int pd = pl/900; int r = pl - pd*900; int ph = r/30; int pw = r - ph*30;
  int d = pd-1, h = ph-1, w = pw-1;
  u16 v = 0;
  if ((unsigned)d < 28u && (unsigned)h < 28u && (unsigned)w < 28u){
    float xv = t1[((size_t)half*LTOT + (d*28+h)*28+w)*192 + t];
    v = f2b(fmaxf(xv*a1[t] + b1[t], 0.f));
  }
  xp2[(size_t)p*192 + t] = v;
}

// ------ conv1: tri-buffered DMA-B / reg-A, counted vmcnt + raw barrier -----
// [r7 WINNER config: ~310us, 3 blocks/CU resident, MfmaUtil 24%]
__global__ __launch_bounds__(256, 3) void k_conv1dma(const u16* __restrict__ xp,
                                                     const u16* __restrict__ wmT,
                                                     const u16* __restrict__ wfT,
                                                     float* __restrict__ outm,
                                                     float* __restrict__ outf){
  __shared__ __align__(16) u16 As[3][64*40];    // 15.4 KB
  __shared__ __align__(16) u16 Bs[3][4*1544];   // 37.1 KB
  int tid = threadIdx.x;
  // bijective XCD swizzle over nwg=686: q=85, r=6
  int b0 = blockIdx.x;
  int xcd = b0 & 7, ii = b0 >> 3;
  int bid = (xcd < 6 ? xcd*86 : 516 + (xcd-6)*85) + ii;
  int half = (bid >= 343) ? 1 : 0;
  int t = bid - half*343;
  const u16* wtb = half ? wfT : wmT;
  float* out = half ? outf : outm;
  int v0 = t*64;
  int sv  = tid>>2;                 // A staging row
  int c8u = (tid&3)*8;
  int av = v0 + sv;
  int d = av/784; int rm2 = av - d*784; int hh = rm2/28; int ww = rm2 - hh*28;
  int pbase = (d*30 + hh)*30 + ww;
  int lane = tid&63, wv = tid>>6;
  int lm = lane&15, lq = lane>>4;
  int nbase = wv*48;

  float4v acc[4][3];
  #pragma unroll
  for (int mt=0; mt<4; mt++)
    #pragma unroll
    for (int nt=0; nt<3; nt++) acc[mt][nt] = (float4v)0.f;

  uint4 a_r;
  auto loadA = [&](int s){
    int tp = s/12, cc = s - tp*12;          // CH = 384/32 = 12
    int td = tp/9, tr = tp - td*9, th = tr/3, tw = tr - th*3;
    int toff = td*900 + th*30 + tw;
    a_r = *(const uint4*)(xp + (size_t)(pbase + toff)*384 + cc*32 + c8u);
  };
  auto dmaB = [&](int buf, int s){
    const u16* bsrc = wtb + ((size_t)(s*4 + wv)*192)*8 + (size_t)lane*8;
    #pragma unroll
    for (int j=0;j<3;j++)
      dma16(bsrc + j*512, &Bs[buf][wv*1544 + j*512]);
  };
  auto writeA = [&](int buf){
    *(uint4*)(&As[buf][sv*40 + c8u]) = a_r;
  };

  // prologue: fill buffers 0 and 1
  loadA(0); dmaB(0, 0); writeA(0);
  loadA(1); dmaB(1, 1); writeA(1);
  asm volatile("s_waitcnt vmcnt(3) lgkmcnt(0)" ::: "memory");
  __builtin_amdgcn_sched_barrier(0);
  __builtin_amdgcn_s_barrier();
  int cur = 0;
  for (int s = 0; s < 324; s++){
    int pf = cur + 2; if (pf >= 3) pf -= 3;
    if (s < 322){ loadA(s+2); dmaB(pf, s+2); }
    short8 aa[4], bb[3];
    #pragma unroll
    for (int mt=0; mt<4; mt++)
      aa[mt] = *(const short8*)(&As[cur][(mt*16 + lm)*40 + lq*8]);
    #pragma unroll
    for (int nt=0; nt<3; nt++)
      bb[nt] = *(const short8*)(&Bs[cur][lq*1544 + (nbase + nt*16 + lm)*8]);
    #pragma unroll
    for (int nt=0; nt<3; nt++)
      #pragma unroll
      for (int mt=0; mt<4; mt++)
        acc[mt][nt] = __builtin_amdgcn_mfma_f32_16x16x32_bf16(aa[mt], bb[nt], acc[mt][nt], 0, 0, 0);
    if (s < 322){
      writeA(pf);
      asm volatile("s_waitcnt vmcnt(3) lgkmcnt(0)" ::: "memory");
      __builtin_amdgcn_sched_barrier(0);
    } else {
      asm volatile("s_waitcnt vmcnt(0) lgkmcnt(0)" ::: "memory");
      __builtin_amdgcn_sched_barrier(0);
    }
    __builtin_amdgcn_s_barrier();
    cur++; if (cur >= 3) cur = 0;
  }
  #pragma unroll
  for (int mt=0; mt<4; mt++)
    #pragma unroll
    for (int nt=0; nt<3; nt++)
      #pragma unroll
      for (int r=0; r<4; r++){
        int row = v0 + mt*16 + lq*4 + r;
        int col = nbase + nt*16 + lm;
        out[(size_t)row*192 + col] = acc[mt][nt][r];
      }
}

// ------ conv2 implicit-GEMM MFMA (verified round-2 structure) --------------
template<int CIN, int COUT>
__global__ __launch_bounds__(256, 4) void k_convmfma(const u16* __restrict__ xpA,
                                                     const u16* __restrict__ xpB,
                                                     const u16* __restrict__ wA,
                                                     const u16* __restrict__ wB,
                                                     float* __restrict__ outA,
                                                     float* __restrict__ outB){
  constexpr int K = 27*CIN;
  constexpr int CH = CIN/32;
  constexpr int STEPS = 27*CH;
  constexpr int NT = COUT/32;
  constexpr int NB8 = COUT/32;
  __shared__ __align__(16) u16 As[2][64*40];
  __shared__ __align__(16) u16 Bs[2][COUT*40];
  int tid = threadIdx.x;
  int b0 = blockIdx.x;
  int xcd = b0 & 7, ii = b0 >> 3;
  int bid = (xcd < 6 ? xcd*86 : 516 + (xcd-6)*85) + ii;
  int which = (bid >= 343) ? 1 : 0;
  int t = bid - which*343;
  const u16* xp  = which ? xpB : xpA;
  const u16* wtb = which ? wB : wA;
  float* out = which ? outB : outA;
  int v0 = t*64;
  int sv  = tid>>2;
  int c8u = (tid&3)*8;
  int av = v0 + sv;
  int d = av/784; int rm2 = av - d*784; int hh = rm2/28; int ww = rm2 - hh*28;
  int pbase = (d*30 + hh)*30 + ww;
  int lane = tid&63, wv = tid>>6;
  int lm = lane&15, lq = lane>>4;
  int mbase = (wv>>1)*32;
  int nbase = (wv&1)*(COUT/2);

  float4v acc[2][NT];
  #pragma unroll
  for (int mt=0; mt<2; mt++)
    #pragma unroll
    for (int nt=0; nt<NT; nt++) acc[mt][nt] = (float4v)0.f;

  uint4 a_r;
  uint2 b_r[NB8];
  auto load_s = [&](int s){
    int tp = s/CH, cc = s - tp*CH;
    int td = tp/9, tr = tp - td*9, th = tr/3, tw = tr - th*3;
    int toff = td*900 + th*30 + tw;
    a_r = *(const uint4*)(xp + (size_t)(pbase + toff)*CIN + cc*32 + c8u);
    #pragma unroll
    for (int j=0;j<NB8;j++){
      int bi = tid + j*256;
      int n = bi>>3, c4 = (bi&7)*4;
      b_r[j] = *(const uint2*)(wtb + (size_t)n*K + s*32 + c4);
    }
  };
  auto write_s = [&](int buf){
    *(uint4*)(&As[buf][sv*40 + c8u]) = a_r;
    #pragma unroll
    for (int j=0;j<NB8;j++){
      int bi = tid + j*256;
      int n = bi>>3, c4 = (bi&7)*4;
      *(uint2*)(&Bs[buf][n*40 + c4]) = b_r[j];
    }
  };

  load_s(0);
  write_s(0);
  __syncthreads();
  for (int s = 0; s < STEPS; s++){
    if (s+1 < STEPS) load_s(s+1);
    int buf = s&1;
    short8 aa[2], bb[NT];
    #pragma unroll
    for (int mt=0; mt<2; mt++)
      aa[mt] = *(const short8*)(&As[buf][(mbase + mt*16 + lm)*40 + lq*8]);
    #pragma unroll
    for (int nt=0; nt<NT; nt++)
      bb[nt] = *(const short8*)(&Bs[buf][(nbase + nt*16 + lm)*40 + lq*8]);
    #pragma unroll
    for (int nt=0; nt<NT; nt++)
      #pragma unroll
      for (int mt=0; mt<2; mt++)
        acc[mt][nt] = __builtin_amdgcn_mfma_f32_16x16x32_bf16(aa[mt], bb[nt], acc[mt][nt], 0, 0, 0);
    if (s+1 < STEPS) write_s((s+1)&1);
    __syncthreads();
  }
  #pragma unroll
  for (int mt=0; mt<2; mt++)
    #pragma unroll
    for (int nt=0; nt<NT; nt++)
      #pragma unroll
      for (int r=0; r<4; r++){
        int row = v0 + mbase + mt*16 + lq*4 + r;
        int col = nbase + nt*16 + lm;
        out[(size_t)row*COUT + col] = acc[mt][nt][r];
      }
}

// ---- generic MFMA GEMM, 64x192 blocks, 4 waves of 32x96 (r2-proven shape) -
// NB = NF/192 n-blocks per m-tile; MRG=1 adds a second pointer set (f-half).
template<int K, int NF, int GATHER, int ASRC, int EPI, int MRG>
__global__ __launch_bounds__(256) void k_gemm(const float* __restrict__ Af,
                                              const u16* __restrict__ Ab,
                                              const u16* __restrict__ B,
                                              const float* __restrict__ bias,
                                              const float* __restrict__ resid,
                                              float* __restrict__ outf,
                                              u16* __restrict__ out16,
                                              u16* __restrict__ out16b,
                                              float scale,
                                              const u16* __restrict__ B2,
                                              const float* __restrict__ bias2,
                                              const float* __restrict__ resid2,
                                              float* __restrict__ outf2,
                                              u16* __restrict__ out162,
                                              u16* __restrict__ out16b2){
  constexpr int STEPS = K/32;
  constexpr int NB = NF/192;
  __shared__ __align__(16) u16 As[2][64*40];
  __shared__ __align__(16) u16 Bs[2][192*40];
  __shared__ int map[64];
  int tid = threadIdx.x;
  int bid = blockIdx.x;
  int mb = bid / NB, nb = bid - mb*NB;
  int v0 = mb*64, ncol0 = nb*192;
  int half = (MRG && v0 >= LTOT) ? 1 : 0;
  const u16* Bx = half ? B2 : B;
  const float* biasx = half ? bias2 : bias;
  const float* residx = half ? resid2 : resid;
  float* outfx = half ? outf2 : outf;
  u16* out16x = half ? out162 : out16;
  u16* out16bx = half ? out16b2 : out16b;
  int vloc = v0 - half*LTOT;
  if (tid < 64){
    int r = vloc + tid;
    int src;
    if (GATHER == 0){
      src = r;
    } else if (GATHER == 1){
      int w = r/343; int n = r - w*343;
      int nd = w>>4, nh = (w>>2)&3, nw = w&3;
      int i = n/49; int rr = n - i*49; int j = rr/7; int k2 = rr - j*7;
      int dd = nd*7 + i + 3; if (dd >= 28) dd -= 28;
      int hh = nh*7 + j + 3; if (hh >= 28) hh -= 28;
      int ww = nw*7 + k2 + 3; if (ww >= 28) ww -= 28;
      src = (dd*28 + hh)*28 + ww;
    } else {
      int l = r;
      int d = l/784; int rm = l - d*784; int y = rm/28; int x = rm - y*28;
      int dp = d-3; if (dp<0) dp+=28;
      int yp = y-3; if (yp<0) yp+=28;
      int xq = x-3; if (xq<0) xq+=28;
      int nd = dp/7, i = dp - nd*7;
      int nh = yp/7, j = yp - nh*7;
      int nw = xq/7, k2 = xq - nw*7;
      src = ((nd*4+nh)*4+nw)*NTOK + (i*7+j)*7 + k2;
    }
    map[tid] = src + half*LTOT;     // A is contiguous across halves
  }
  __syncthreads();
  int sv = tid>>2, c8 = (tid&3)*8;
  int arow = map[sv];
  int lane = tid&63, wv = tid>>6;
  int lm = lane&15, lq = lane>>4;
  int mbase = (wv>>1)*32, nbase = (wv&1)*96;

  float4v acc[2][6];
  #pragma unroll
  for (int mt=0; mt<2; mt++)
    #pragma unroll
    for (int nt=0; nt<6; nt++) acc[mt][nt] = (float4v)0.f;

  float4 afr0, afr1; uint4 abr; uint2 bvr[6];
  auto load_s = [&](int s){
    if (ASRC == 0){
      const float* ap = Af + (size_t)arow*K + s*32 + c8;
      afr0 = *(const float4*)ap;
      afr1 = *(const float4*)(ap+4);
    } else {
      abr = *(const uint4*)(Ab + (size_t)arow*K + s*32 + c8);
    }
    #pragma unroll
    for (int j=0;j<6;j++){
      int bi = tid + j*256;
      int n = bi>>3, c4 = (bi&7)*4;
      bvr[j] = *(const uint2*)(Bx + (size_t)(ncol0 + n)*K + s*32 + c4);
    }
  };
  auto write_s = [&](int buf){
    if (ASRC == 0){
      uint4 pk;
      pk.x = (u32)f2b(afr0.x) | ((u32)f2b(afr0.y)<<16);
      pk.y = (u32)f2b(afr0.z) | ((u32)f2b(afr0.w)<<16);
      pk.z = (u32)f2b(afr1.x) | ((u32)f2b(afr1.y)<<16);
      pk.w = (u32)f2b(afr1.z) | ((u32)f2b(afr1.w)<<16);
      *(uint4*)(&As[buf][sv*40 + c8]) = pk;
    } else {
      *(uint4*)(&As[buf][sv*40 + c8]) = abr;
    }
    #pragma unroll
    for (int j=0;j<6;j++){
      int bi = tid + j*256;
      int n = bi>>3, c4 = (bi&7)*4;
      *(uint2*)(&Bs[buf][n*40 + c4]) = bvr[j];
    }
  };

  load_s(0);
  write_s(0);
  __syncthreads();
  for (int s = 0; s < STEPS; s++){
    if (s+1 < STEPS) load_s(s+1);
    int buf = s&1;
    short8 aa[2], bb[6];
    #pragma unroll
    for (int mt=0; mt<2; mt++)
      aa[mt] = *(const short8*)(&As[buf][(mbase + mt*16 + lm)*40 + lq*8]);
    #pragma unroll
    for (int nt=0; nt<6; nt++)
      bb[nt] = *(const short8*)(&Bs[buf][(nbase + nt*16 + lm)*40 + lq*8]);
    #pragma unroll
    for (int nt=0; nt<6; nt++)
      #pragma unroll
      for (int mt=0; mt<2; mt++)
        acc[mt][nt] = __builtin_amdgcn_mfma_f32_16x16x32_bf16(aa[mt], bb[nt], acc[mt][nt], 0, 0, 0);
    if (s+1 < STEPS) write_s((s+1)&1);
    __syncthreads();
  }
  // epilogue
  float bv[6];
  #pragma unroll
  for (int nt=0; nt<6; nt++) bv[nt] = biasx ? biasx[ncol0 + nbase + nt*16 + lm] : 0.f;
  #pragma unroll
  for (int mt=0; mt<2; mt++){
    #pragma unroll
    for (int r=0; r<4; r++){
      int row = v0 + mbase + mt*16 + lq*4 + r;
      int rowl = row - half*LTOT;
      if (EPI == 0 || EPI == 3){
        int w = rowl/343; int tok = rowl - w*343;
        #pragma unroll
        for (int nt=0; nt<6; nt++){
          int col = ncol0 + nbase + nt*16 + lm;
          float val = (acc[mt][nt][r] + bv[nt]) * scale;
          if (EPI == 0){
            int h = col>>5, c = col&31;
            out16x[((size_t)(w*6 + h)*343 + tok)*32 + c] = f2b(val);
          } else {
            u16* dst = (col < 192) ? out16x : out16bx;
            int cc = (col < 192) ? col : col - 192;
            int h = cc>>5, c = cc&31;
            dst[((size_t)(w*6 + h)*343 + tok)*32 + c] = f2b(val);
          }
        }
      } else if (EPI == 1){
        #pragma unroll
        for (int nt=0; nt<6; nt++){
          int col = ncol0 + nbase + nt*16 + lm;
          size_t o = (size_t)rowl*NF + col;
          outfx[o] = acc[mt][nt][r] + bv[nt] + residx[o];
        }
      } else {
        #pragma unroll
        for (int nt=0; nt<6; nt++){
          int col = ncol0 + nbase + nt*16 + lm;
          float v = acc[mt][nt][r] + bv[nt];
          float gl = 0.5f*v*(1.f + erff(v*0.70710678118f));
          out16[(size_t)row*NF + col] = f2b(gl);   // fc1: single global hs
        }
      }
    }
  }
}

// ---- BN stats, merged m+f: grid 128, x = contiguous [2L][C] ---------------
__global__ __launch_bounds__(192) void k_bnsum(const float* __restrict__ x, int C,
                                               float* __restrict__ psum){
  int bid = blockIdx.x, t = threadIdx.x;
  int rpi = 192/C;
  int c  = (C==192) ? t : (t % 96);
  int ro = (C==192) ? 0 : (t / 96);
  float s=0.f, s2=0.f;
  int base = bid*343;
  for (int r = ro; r < 343; r += rpi){
    float v = x[(size_t)(base+r)*C + c];
    s += v; s2 += v*v;
  }
  psum[(size_t)bid*384 + t]       = s;
  psum[(size_t)bid*384 + 192 + t] = s2;
}
__global__ void k_bnfin2(const float* __restrict__ psum, int C,
                         const float* __restrict__ g0, const float* __restrict__ bb0,
                         const float* __restrict__ g1, const float* __restrict__ bb1,
                         float* a0, float* b0o, float* a1, float* b1o){
  int h = blockIdx.x;
  int c = threadIdx.x;
  if (c >= C) return;
  const float* g  = h ? g1 : g0;
  const float* bb = h ? bb1 : bb0;
  float* ao = h ? a1 : a0;
  float* bo = h ? b1o : b0o;
  const float* ps = psum + (size_t)h*64*384;
  int slots = 192/C;
  float s=0.f, s2=0.f;
  for (int b=0; b<64; b++)
    for (int k=0; k<slots; k++){
      s  += ps[(size_t)b*384 + k*C + c];
      s2 += ps[(size_t)b*384 + 192 + k*C + c];
    }
  float mu = s/(float)LTOT;
  float var = s2/(float)LTOT - mu*mu;
  float rstd = rsqrtf(var + 1e-5f);
  float aa = rstd * g[c];
  ao[c] = aa;
  bo[c] = bb[c] - mu*aa;
}

// ------------- conv3 1x1x1 merged m+f: grid 2L -----------------------------
__global__ __launch_bounds__(96) void k_flow(const float* __restrict__ t2,
                                             const float* __restrict__ a2b,
                                             const float* __restrict__ w3m,
                                             const float* __restrict__ w3f,
                                             float* __restrict__ flow){
  __shared__ float xr[96];
  int l = blockIdx.x; int t = threadIdx.x;
  int half = l >= LTOT; int ll = l - half*LTOT;
  const float* a2 = a2b + half*192; const float* b2 = a2 + 96;
  const float* w3 = half ? w3f : w3m;
  float xv = t2[(size_t)l*96 + t];
  xr[t] = fmaxf(xv*a2[t] + b2[t], 0.f);
  __syncthreads();
  if (t < 18){
    float acc = 0.f;
    for (int c=0;c<96;c++) acc += xr[c]*w3[t*96 + c];
    flow[((size_t)half*18 + t)*LTOT + ll] = acc;
  }
}

// ------------- trilinear warp merged m+f: grid 2L --------------------------
__global__ __launch_bounds__(192) void k_warp(const float* __restrict__ src,
                                              const float* __restrict__ flow, float* __restrict__ dst){
  int l = blockIdx.x; int tid = threadIdx.x; int hh = tid>>5;
  int half = l >= LTOT; int ll = l - half*LTOT;
  const float* s_ = src + (size_t)half*LTOT*192;
  int d = ll/784; int rm = ll - d*784; int y = rm/28; int x = rm - y*28;
  float fd = flow[((size_t)half*18 + hh*3+0)*LTOT + ll];
  float fy = flow[((size_t)half*18 + hh*3+1)*LTOT + ll];
  float fx = flow[((size_t)half*18 + hh*3+2)*LTOT + ll];
  float cd = fminf(fmaxf((float)d + fd, 0.f), 27.f);
  float cy = fminf(fmaxf((float)y + fy, 0.f), 27.f);
  float cx = fminf(fmaxf((float)x + fx, 0.f), 27.f);
  int d0 = (int)floorf(cd); int d1 = min(d0+1, 27);
  int y0 = (int)floorf(cy); int y1 = min(y0+1, 27);
  int x0 = (int)floorf(cx); int x1 = min(x0+1, 27);
  float wd = cd - (float)d0, wy = cy - (float)y0, wx = cx - (float)x0;
  #define SMP(di,yi,xi) s_[(size_t)(((di)*28+(yi))*28+(xi))*192 + tid]
  float v000 = SMP(d0,y0,x0), v001 = SMP(d0,y0,x1), v010 = SMP(d0,y1,x0), v011 = SMP(d0,y1,x1);
  float v100 = SMP(d1,y0,x0), v101 = SMP(d1,y0,x1), v110 = SMP(d1,y1,x0), v111 = SMP(d1,y1,x1);
  #undef SMP
  float o = v000*(1-wd)*(1-wy)*(1-wx) + v001*(1-wd)*(1-wy)*wx
          + v010*(1-wd)*wy*(1-wx)     + v011*(1-wd)*wy*wx
          + v100*wd*(1-wy)*(1-wx)     + v101*wd*(1-wy)*wx
          + v110*wd*wy*(1-wx)         + v111*wd*wy*wx;
  dst[(size_t)l*192 + tid] = o;
}

// ------------ MFMA attention, qg merged 3-way: grid 1536 -------------------
__global__ __launch_bounds__(256) void k_attmfma(const u16* __restrict__ Q1,
                                                 const u16* __restrict__ K1,
                                                 const u16* __restrict__ V1,
                                                 const u16* __restrict__ Q2,
                                                 const u16* __restrict__ K2,
                                                 const u16* __restrict__ V2,
                                                 const float* __restrict__ bm,
                                                 float* __restrict__ ctx1,
                                                 float* __restrict__ ctx2){
  __shared__ __align__(16) u16 Kl[352*40];      // [key][40]
  __shared__ __align__(16) u16 Vt[32*360];      // [dim][360]
  __shared__ __align__(16) u16 Pl[4][2][16*40]; // per-wave, dbuf
  int bid0 = blockIdx.x;                        // [0, 1536)
  int halfsel = bid0 >= 768;
  int bid = bid0 - halfsel*768;                 // [0, 768)
  int wh = bid >> 1;                            // [0, 384)
  int qg2 = bid & 1;                            // q half: tiles 0-11 / 12-21
  const u16* Q = halfsel ? Q2 : Q1;
  const u16* K = halfsel ? K2 : K1;
  const u16* V = halfsel ? V2 : V1;
  float* ctx = halfsel ? ctx2 : ctx1;
  int w = wh/6, h = wh - w*6;
  int tid = threadIdx.x;
  int nd = w>>4, nh = (w>>2)&3, nw = w&3;
  int type = ((nd==3)?4:0) | ((nh==3)?2:0) | ((nw==3)?1:0);
  const u16* kb = K + (size_t)wh*10976;
  const u16* vbp = V + (size_t)wh*10976;
  for (int idx=tid; idx<343*4; idx+=256){
    int row = idx>>2, c8 = (idx&3)*8;
    uint4 val = *(const uint4*)(kb + row*32 + c8);
    *(uint4*)(&Kl[row*40 + c8]) = val;
  }
  for (int idx=tid; idx<9*40; idx+=256) Kl[343*40 + idx] = 0;
  for (int idx=tid; idx<343*4; idx+=256){
    int row = idx>>2, c8 = (idx&3)*8;
    uint4 val = *(const uint4*)(vbp + row*32 + c8);
    const u16* pv = (const u16*)&val;
    #pragma unroll
    for (int j=0;j<8;j++) Vt[(c8+j)*360 + row] = pv[j];
  }
  for (int idx=tid; idx<32*17; idx+=256){
    int dd = idx/17, cc = 343 + idx - (idx/17)*17;
    Vt[dd*360 + cc] = 0;
  }
  __syncthreads();
  int lane = tid&63, wv = tid>>6;
  int lm = lane&15, lq = lane>>4;
  const float* bmh = bm + (size_t)(type*6 + h)*123904;
  for (int rnd = 0; rnd < 3; rnd++){
    int qt = qg2*12 + rnd*4 + wv;
    if (qt < 22){
      int q0 = qt*16;
      short8 bq = *(const short8*)(Q + (size_t)wh*10976 + (q0+lm)*32 + lq*8);
      float4v sc[22];
      #pragma unroll
      for (int kt=0; kt<22; kt++){
        short8 ak = *(const short8*)(&Kl[(kt*16+lm)*40 + lq*8]);
        sc[kt] = __builtin_amdgcn_mfma_f32_16x16x32_bf16(ak, bq, (float4v)0.f, 0, 0, 0);
      }
      const float* bcol = bmh + q0 + lm;
      float mx = -3.0e38f;
      #pragma unroll
      for (int kt=0; kt<22; kt++){
        #pragma unroll
        for (int r=0; r<4; r++){
          int key = kt*16 + lq*4 + r;
          float s = sc[kt][r] + bcol[(size_t)key*352];
          sc[kt][r] = s;
          mx = fmaxf(mx, s);
        }
      }
      mx = fmaxf(mx, __shfl_xor(mx, 16));
      mx = fmaxf(mx, __shfl_xor(mx, 32));
      float sm = 0.f;
      #pragma unroll
      for (int kt=0; kt<22; kt++){
        #pragma unroll
        for (int r=0; r<4; r++){
          float p = __expf(sc[kt][r] - mx);
          sc[kt][r] = p;
          sm += p;
        }
      }
      sm += __shfl_xor(sm, 16);
      sm += __shfl_xor(sm, 32);
      float inv = 1.f/sm;
      float4v o0 = (float4v)0.f, o1 = (float4v)0.f;
      #pragma unroll
      for (int s=0; s<11; s++){
        u16* pw = &Pl[wv][s&1][0];
        #pragma unroll
        for (int hf=0; hf<2; hf++){
          int kt = 2*s + hf;
          uint2 pv2;
          pv2.x = (u32)f2b(sc[kt][0]) | ((u32)f2b(sc[kt][1])<<16);
          pv2.y = (u32)f2b(sc[kt][2]) | ((u32)f2b(sc[kt][3])<<16);
          *(uint2*)(&pw[lm*40 + hf*16 + lq*4]) = pv2;
        }
        short8 bp = *(const short8*)(&pw[lm*40 + lq*8]);
        short8 a0 = *(const short8*)(&Vt[lm*360 + s*32 + lq*8]);
        short8 a1 = *(const short8*)(&Vt[(16+lm)*360 + s*32 + lq*8]);
        o0 = __builtin_amdgcn_mfma_f32_16x16x32_bf16(a0, bp, o0, 0, 0, 0);
        o1 = __builtin_amdgcn_mfma_f32_16x16x32_bf16(a1, bp, o1, 0, 0, 0);
      }
      int query = q0 + lm;
      if (query < 343){
        float* ob = ctx + ((size_t)w*NTOK + query)*192 + h*32;
        float4 t0, t1v;
        t0.x = o0[0]*inv; t0.y = o0[1]*inv; t0.z = o0[2]*inv; t0.w = o0[3]*inv;
        t1v.x = o1[0]*inv; t1v.y = o1[1]*inv; t1v.z = o1[2]*inv; t1v.w = o1[3]*inv;
        *(float4*)(ob + lq*4) = t0;
        *(float4*)(ob + 16 + lq*4) = t1v;
      }
    }
  }
}

// ===========================================================================
extern "C" void kernel_launch(void* const* d_in, const int* in_sizes, int n_in,
                              void* d_out, int out_size, void* d_ws, size_t ws_size,
                              hipStream_t stream){
  const float* mov     = (const float*)d_in[0];
  const float* fix     = (const float*)d_in[1];
  const float* n1g     = (const float*)d_in[2];
  const float* n1b     = (const float*)d_in[3];
  const float* offm_w1 = (const float*)d_in[4];
  const float* offm_g1 = (const float*)d_in[5];
  const float* offm_b1 = (const float*)d_in[6];
  const float* offm_w2 = (const float*)d_in[7];
  const float* offm_g2 = (const float*)d_in[8];
  const float* offm_b2 = (const float*)d_in[9];
  const float* offm_w3 = (const float*)d_in[10];
  const float* offf_w1 = (const float*)d_in[11];
  const float* offf_g1 = (const float*)d_in[12];
  const float* offf_b1 = (const float*)d_in[13];
  const float* offf_w2 = (const float*)d_in[14];
  const float* offf_g2 = (const float*)d_in[15];
  const float* offf_b2 = (const float*)d_in[16];
  const float* offf_w3 = (const float*)d_in[17];
  const float* mq_w    = (const float*)d_in[18];
  const float* mkv_w   = (const float*)d_in[19];
  const float* fq_w    = (const float*)d_in[20];
  const float* fkv_w   = (const float*)d_in[21];
  const float* mproj_w = (const float*)d_in[22];
  const float* fproj_w = (const float*)d_in[23];
  const float* mq_b    = (const float*)d_in[24];
  const float* mkv_b   = (const float*)d_in[25];
  const float* fq_b    = (const float*)d_in[26];
  const float* fkv_b   = (const float*)d_in[27];
  const float* mproj_b = (const float*)d_in[28];
  const float* fproj_b = (const float*)d_in[29];
  const float* rpbt    = (const float*)d_in[30];
  const float* n2g     = (const float*)d_in[31];
  const float* n2b     = (const float*)d_in[32];
  const float* fc1_w   = (const float*)d_in[33];
  const float* fc1_b   = (const float*)d_in[34];
  const float* fc2_w   = (const float*)d_in[35];
  const float* fc2_b   = (const float*)d_in[36];
  float* outp = (float*)d_out;

  float* W = (float*)d_ws;
  const size_t L192 = (size_t)LTOT*192;   // floats per region (16.86 MB)
  // conv-phase layout:
  float* m_   = W;                         // region 0
  float* f_   = W + 1*L192;                // region 1
  float* t1   = W + 2*L192;                // regions 2,3 ([2L][192])
  u16* xp     = (u16*)(W + 4*L192);        // 27000*384 u16
  u16* xp2    = xp + (size_t)27000*384;    // 54000*192 u16, contiguous m|f
  float* sb   = W + 6*L192 + 3000000;      // stats block
  float* a1m = sb,       *b1m = sb+192;
  float* a1f = sb+384,   *b1f = sb+576;
  float* a2m = sb+768,   *b2m = sb+864;
  float* a2f = sb+960,   *b2f = sb+1056;
  float* psum = sb + 1536;                 // 128*384 floats
  float* flowm = W + 6*L192 + 3100000;     // [36][LTOT]
  float* t2   = W + 7*L192;                // [2L][96]
  u16* wt1m = (u16*)(W + 8*L192);          // conv weights, region 8
  u16* wt1f = wt1m + 192*10368;
  u16* wt2m = wt1f + 192*10368;
  u16* wt2f = wt2m + 96*5184;
  // post-conv reuse:
  float* dmov = W + 4*L192;                // region 4
  float* dfix = W + 5*L192;                // region 5
  float* ctxm = dmov; float* ctxf = dfix;
  float* mout = m_;   float* fout = f_;
  u16* QMb = (u16*)(W + 6*L192);
  u16* QFb = (u16*)(W + 7*L192);
  u16* Kmb = (u16*)(W + 2*L192);
  u16* Vmb = (u16*)(W + 3*L192);
  u16* Kfb = (u16*)(W + 8*L192);
  u16* Vfb = (u16*)(W + 9*L192);
  float* bm = W;
  u16* wq_m  = (u16*)(W + 9*L192) + 4214784;
  u16* wq_f  = wq_m  + 36864;
  u16* wkv_m = wq_f  + 36864;
  u16* wkv_f = wkv_m + 73728;
  u16* wpj_m = wkv_f + 73728;
  u16* wpj_f = wpj_m + 36864;
  u16* wfc1  = wpj_f + 36864;
  u16* wfc2  = wfc1  + 147456;
  u16* hs16  = (u16*)(W + 2*L192);         // [2L][768] regions 2-5
  float* lnbuf = W + 6*L192;               // [2L][192] regions 6,7

  // weight prep (3 launches)
  k_prepw1b<<<(2*192*10368+255)/256, 256, 0, stream>>>(offm_w1, offf_w1, wt1m, wt1f);
  k_prepw2b<<<(2*96*5184+255)/256, 256, 0, stream>>>(offm_w2, offf_w2, wt2m, wt2f);
  k_prepwb8<<<2304, 256, 0, stream>>>(mq_w, fq_w, mkv_w, fkv_w, mproj_w, fproj_w, fc1_w, fc2_w,
                                      wq_m, wq_f, wkv_m, wkv_f, wpj_m, wpj_f, wfc1, wfc2);
  // layernorm1
  k_ln<<<2*LTOT, 64, 0, stream>>>(mov, fix, n1g, n1b, m_, f_);
  // padded bf16 volume [m|f]
  k_pad1<<<27000, 192, 0, stream>>>(m_, f_, xp);
  // conv1 (r7 winner: 4-wave 64x48, tri-buffered, counted vmcnt)
  k_conv1dma<<<686, 256, 0, stream>>>(xp, wt1m, wt1f, t1, t1 + 2*L192);
  k_bnsum<<<128, 192, 0, stream>>>(t1, 192, psum);
  k_bnfin2<<<2, 192, 0, stream>>>(psum, 192, offm_g1, offm_b1, offf_g1, offf_b1, a1m, b1m, a1f, b1f);
  k_pad2<<<54000, 192, 0, stream>>>(t1, sb, xp2);
  // conv2 (m+f halves of contiguous xp2)
  k_convmfma<192,96><<<686, 256, 0, stream>>>(xp2, xp2 + (size_t)27000*192, wt2m, wt2f,
                                              t2, t2 + (size_t)LTOT*96);
  k_bnsum<<<128, 192, 0, stream>>>(t2, 96, psum);
  k_bnfin2<<<2, 96, 0, stream>>>(psum, 96, offm_g2, offm_b2, offf_g2, offf_b2, a2m, b2m, a2f, b2f);
  k_flow<<<2*LTOT, 96, 0, stream>>>(t2, sb+768, offm_w3, offf_w3, flowm);
  // deformable warp (merged)
  k_warp<<<2*LTOT, 192, 0, stream>>>(m_, flowm, dmov);
  // windowed projections (merged m+f, 64x192 blocks)
  const float scale = 0.17677669529663687f; // 32^-0.5
  k_gemm<192,192,1,0,0,1><<<2*343, 256, 0, stream>>>(dmov, nullptr, wq_m, mq_b, nullptr, nullptr, QMb, nullptr, scale,
                                                     wq_f, fq_b, nullptr, nullptr, QFb, nullptr);
  k_gemm<192,384,1,0,3,1><<<2*343*2, 256, 0, stream>>>(m_, nullptr, wkv_m, mkv_b, nullptr, nullptr, Kmb, Vmb, 1.f,
                                                       wkv_f, fkv_b, nullptr, nullptr, Kfb, Vfb);
  // bias matrix (m_/f_ now dead)
  k_prepbias<<<(48*123904+255)/256, 256, 0, stream>>>(rpbt, bm);
  // attention merged (qg 3-way): mo = attend(dfQ, mK, mV); fo = attend(dmQ, fK, fV)
  k_attmfma<<<1536, 256, 0, stream>>>(QFb, Kmb, Vmb, QMb, Kfb, Vfb, bm, ctxm, ctxf);
  // proj + residual + window-reverse (merged)
  k_gemm<192,192,2,0,1,1><<<2*343, 256, 0, stream>>>(ctxm, nullptr, wpj_m, mproj_b, mov, mout, nullptr, nullptr, 1.f,
                                                     wpj_f, fproj_b, fix, fout, nullptr, nullptr);
  // MLP both halves (contiguous rows)
  k_ln1<<<2*LTOT, 64, 0, stream>>>(mout, n2g, n2b, lnbuf);
  k_gemm<192,768,0,0,2,0><<<2*343*4, 256, 0, stream>>>(lnbuf, nullptr, wfc1, fc1_b, nullptr, nullptr, hs16, nullptr, 1.f,
                                                       nullptr, nullptr, nullptr, nullptr, nullptr, nullptr);
  k_gemm<768,192,0,1,1,0><<<2*343, 256, 0, stream>>>(nullptr, hs16, wfc2, fc2_b, mout, outp, nullptr, nullptr, 1.f,
                                                     nullptr, nullptr, nullptr, nullptr, nullptr, nullptr);
}